// Round 1
// baseline (2033.444 us; speedup 1.0000x reference)
//
#include <hip/hip_runtime.h>
#include <math.h>

#define N_NODES 50000
#define N_EDGES 800000
#define H       128
#define MSG_IN  292     // 2*H + 32 (edge_attr) + 4 (tiled dist^2)
#define ME      64      // edges per block
#define MN      64      // nodes per block
#define HS      132     // padded stride for 128-wide LDS buffers
#define MSOFF   (ME*HS) // msg region offset inside edge-kernel LDS union

__device__ __forceinline__ float silu_f(float x) {
    return x / (1.0f + expf(-x));
}

// acc[i][0..3] += xs * wv.{x,y,z,w}
#define FMA4(i, xs, wv)                              \
    acc[i][0] = fmaf((xs), (wv).x, acc[i][0]);       \
    acc[i][1] = fmaf((xs), (wv).y, acc[i][1]);       \
    acc[i][2] = fmaf((xs), (wv).z, acc[i][2]);       \
    acc[i][3] = fmaf((xs), (wv).w, acc[i][3]);

// Register-blocked GEMM: each thread computes acc[8 edges][4 cols].
// SPTR: LDS input base, SSTRIDE: row stride (floats), WPTR: [KDIM][128] row-major
// weights in global, KDIM: reduction length. Uses c4 (t&31), eb ((t>>5)*8).
#define GEMM(SPTR, SSTRIDE, WPTR, KDIM)                                   \
    for (int k0 = 0; k0 < (KDIM); k0 += 4) {                              \
        const float4 wa = *(const float4*)&(WPTR)[(k0+0)*H + 4*c4];       \
        const float4 wb = *(const float4*)&(WPTR)[(k0+1)*H + 4*c4];       \
        const float4 wc = *(const float4*)&(WPTR)[(k0+2)*H + 4*c4];       \
        const float4 wd = *(const float4*)&(WPTR)[(k0+3)*H + 4*c4];       \
        _Pragma("unroll")                                                 \
        for (int i = 0; i < 8; ++i) {                                     \
            const float4 x = *(const float4*)&(SPTR)[(eb+i)*(SSTRIDE) + k0]; \
            FMA4(i, x.x, wa) FMA4(i, x.y, wb)                             \
            FMA4(i, x.z, wc) FMA4(i, x.w, wd)                             \
        }                                                                 \
    }

#define ACC_INIT(BPTR)                                                    \
    {                                                                     \
        const float4 bb = *(const float4*)&(BPTR)[4*c4];                  \
        _Pragma("unroll")                                                 \
        for (int i = 0; i < 8; ++i) {                                     \
            acc[i][0]=bb.x; acc[i][1]=bb.y; acc[i][2]=bb.z; acc[i][3]=bb.w; \
        }                                                                 \
    }

// ---------------------------------------------------------------------------
// Edge kernel: fused gather -> msg MLP -> coff MLP -> atomic segment sums
// ---------------------------------------------------------------------------
__global__ __launch_bounds__(256, 2) void edge_kernel(
    const float* __restrict__ feat, const float* __restrict__ pos,
    const int*   __restrict__ eidx, const float* __restrict__ eattr,
    const float* __restrict__ mw1, const float* __restrict__ mb1,
    const float* __restrict__ mw2, const float* __restrict__ mb2,
    const float* __restrict__ cw1, const float* __restrict__ cb1,
    const float* __restrict__ cw2, const float* __restrict__ cb2,
    float* __restrict__ agg_msg, float* __restrict__ agg_vec,
    float* __restrict__ cnt)
{
    // Union buffer: phase 1 holds X[64][296]; phase 2+ holds h/h2 [64][132]
    // at offset 0 and msg [64][132] at MSOFF. 64*296*4 = 75776 B.
    __shared__ float S[ME * 296];
    __shared__ float unitS[ME][3];
    __shared__ float dsqS[ME];
    __shared__ int   rowS[ME];
    __shared__ int   colS[ME];
    __shared__ float coffS[ME][4];

    const int t  = threadIdx.x;
    const int e0 = blockIdx.x * ME;   // E divisible by 64 -> no tail

    // --- geometry (one thread per edge) ---
    if (t < ME) {
        const int r = eidx[e0 + t];
        const int c = eidx[N_EDGES + e0 + t];
        rowS[t] = r; colS[t] = c;
        const float dx = pos[r*3+0] - pos[c*3+0];
        const float dy = pos[r*3+1] - pos[c*3+1];
        const float dz = pos[r*3+2] - pos[c*3+2];
        const float dsq = dx*dx + dy*dy + dz*dz;
        const float nrm = fmaxf(sqrtf(dsq), 1e-8f);
        unitS[t][0] = dx / nrm;
        unitS[t][1] = dy / nrm;
        unitS[t][2] = dz / nrm;
        dsqS[t] = dsq;
    }
    __syncthreads();

    // --- build X tile: [feat[row] | feat[col] | edge_attr | dsq x4] ---
    const float4* feat4 = (const float4*)feat;
    #pragma unroll
    for (int s = 0; s < 8; ++s) {
        const int flat = t + 256 * s;          // 0..2047
        const int e = flat >> 5, q = flat & 31;
        const float4 vr = feat4[(size_t)rowS[e] * 32 + q];
        *(float4*)&S[e*296 + 4*q] = vr;
        const float4 vc = feat4[(size_t)colS[e] * 32 + q];
        *(float4*)&S[e*296 + 128 + 4*q] = vc;
    }
    const float4* ea4 = (const float4*)eattr;
    #pragma unroll
    for (int s = 0; s < 2; ++s) {
        const int flat = t + 256 * s;          // 0..511
        const int e = flat >> 3, q = flat & 7;
        const float4 v = ea4[(size_t)(e0 + e) * 8 + q];
        *(float4*)&S[e*296 + 256 + 4*q] = v;
    }
    if (t < ME) {
        const float d = dsqS[t];
        S[t*296+288] = d; S[t*296+289] = d; S[t*296+290] = d; S[t*296+291] = d;
    }
    __syncthreads();

    const int c4 = t & 31;
    const int eb = (t >> 5) * 8;
    float acc[8][4];

    // ---- GEMM1: h = silu(X @ mw1 + mb1) ----
    ACC_INIT(mb1)
    GEMM(S, 296, mw1, MSG_IN)
    __syncthreads();                 // all X reads done before overwrite
    #pragma unroll
    for (int i = 0; i < 8; ++i) {
        float4 o;
        o.x = silu_f(acc[i][0]); o.y = silu_f(acc[i][1]);
        o.z = silu_f(acc[i][2]); o.w = silu_f(acc[i][3]);
        *(float4*)&S[(eb+i)*HS + 4*c4] = o;
    }
    __syncthreads();

    // ---- GEMM2: msg = h @ mw2 + mb2 (no activation) ----
    ACC_INIT(mb2)
    GEMM(S, HS, mw2, H)
    #pragma unroll                   // msg region disjoint from h -> no barrier needed
    for (int i = 0; i < 8; ++i) {
        float4 o;
        o.x = acc[i][0]; o.y = acc[i][1]; o.z = acc[i][2]; o.w = acc[i][3];
        *(float4*)&S[MSOFF + (eb+i)*HS + 4*c4] = o;
    }
    __syncthreads();

    // ---- GEMM3: h2 = silu(msg @ cw1 + cb1), overwrite h region ----
    ACC_INIT(cb1)
    GEMM(S + MSOFF, HS, cw1, H)
    // h-region reads (GEMM2) all completed before previous barrier -> safe
    #pragma unroll
    for (int i = 0; i < 8; ++i) {
        float4 o;
        o.x = silu_f(acc[i][0]); o.y = silu_f(acc[i][1]);
        o.z = silu_f(acc[i][2]); o.w = silu_f(acc[i][3]);
        *(float4*)&S[(eb+i)*HS + 4*c4] = o;
    }
    __syncthreads();

    // ---- GEMM4: coff = h2 @ cw2 + cb2  (cw2 is [128][4]) ----
    {
        const int e = t >> 2, c = t & 3;
        float a = cb2[c];
        for (int k = 0; k < H; ++k) a = fmaf(S[e*HS + k], cw2[k*4 + c], a);
        coffS[e][c] = a;
    }
    __syncthreads();

    // ---- atomic segment sums ----
    for (int s = 0; s < 32; ++s) {
        const int flat = t + 256 * s;          // 0..8191
        const int e = flat >> 7, c = flat & 127;
        atomicAdd(&agg_msg[(size_t)rowS[e]*H + c], S[MSOFF + e*HS + c]);
    }
    for (int flat = t; flat < ME*12; flat += 256) {
        const int e = flat / 12, m = flat % 12;
        atomicAdd(&agg_vec[(size_t)rowS[e]*12 + m],
                  coffS[e][m/3] * unitS[e][m%3]);
    }
    if (t < ME) atomicAdd(&cnt[rowS[t]], 1.0f);
}

// ---------------------------------------------------------------------------
// Node kernel: vn_feat = silu-MLP(feat) + MLP(agg_mean); vn_pos = tile(pos)+agg
// ---------------------------------------------------------------------------
__global__ __launch_bounds__(256, 2) void node_kernel(
    const float* __restrict__ feat, const float* __restrict__ pos,
    const float* __restrict__ fw1, const float* __restrict__ fb1,
    const float* __restrict__ fw2, const float* __restrict__ fb2,
    const float* __restrict__ vw1, const float* __restrict__ vb1,
    const float* __restrict__ vw2, const float* __restrict__ vb2,
    const float* __restrict__ agg_msg, const float* __restrict__ agg_vec,
    const float* __restrict__ cnt, float* __restrict__ out)
{
    __shared__ float A[MN*HS];
    __shared__ float B[MN*HS];
    __shared__ float invS[MN];

    const int t  = threadIdx.x;
    const int n0 = blockIdx.x * MN;
    const int c4 = t & 31;
    const int eb = (t >> 5) * 8;

    const float4* feat4 = (const float4*)feat;
    #pragma unroll
    for (int s = 0; s < 8; ++s) {
        const int flat = t + 256*s;
        const int e = flat >> 5, q = flat & 31;
        const int node = n0 + e;
        float4 v = make_float4(0.f, 0.f, 0.f, 0.f);
        if (node < N_NODES) v = feat4[(size_t)node*32 + q];
        *(float4*)&A[e*HS + 4*q] = v;
    }
    if (t < MN) {
        const int node = n0 + t;
        const float c = (node < N_NODES) ? cnt[node] : 1.0f;
        invS[t] = 1.0f / fmaxf(c, 1.0f);
    }
    __syncthreads();

    float acc[8][4];

    // fi layer 1: B = silu(A @ fw1 + fb1)
    ACC_INIT(fb1)
    GEMM(A, HS, fw1, H)
    #pragma unroll
    for (int i = 0; i < 8; ++i) {
        float4 o;
        o.x = silu_f(acc[i][0]); o.y = silu_f(acc[i][1]);
        o.z = silu_f(acc[i][2]); o.w = silu_f(acc[i][3]);
        *(float4*)&B[(eb+i)*HS + 4*c4] = o;
    }
    __syncthreads();

    // fi layer 2: A = silu(B @ fw2 + fb2)   (vn_feat init; A reads all done)
    ACC_INIT(fb2)
    GEMM(B, HS, fw2, H)
    #pragma unroll
    for (int i = 0; i < 8; ++i) {
        float4 o;
        o.x = silu_f(acc[i][0]); o.y = silu_f(acc[i][1]);
        o.z = silu_f(acc[i][2]); o.w = silu_f(acc[i][3]);
        *(float4*)&A[(eb+i)*HS + 4*c4] = o;
    }
    __syncthreads();               // B reads done before overwrite

    // load agg_feat mean tile into B
    const float4* agg4 = (const float4*)agg_msg;
    #pragma unroll
    for (int s = 0; s < 8; ++s) {
        const int flat = t + 256*s;
        const int e = flat >> 5, q = flat & 31;
        const int node = n0 + e;
        float4 v = make_float4(0.f, 0.f, 0.f, 0.f);
        if (node < N_NODES) v = agg4[(size_t)node*32 + q];
        const float iv = invS[e];
        v.x *= iv; v.y *= iv; v.z *= iv; v.w *= iv;
        *(float4*)&B[e*HS + 4*q] = v;
    }
    __syncthreads();

    // vf layer 1: B = silu(B @ vw1 + vb1)
    ACC_INIT(vb1)
    GEMM(B, HS, vw1, H)
    __syncthreads();               // all B reads done before overwrite
    #pragma unroll
    for (int i = 0; i < 8; ++i) {
        float4 o;
        o.x = silu_f(acc[i][0]); o.y = silu_f(acc[i][1]);
        o.z = silu_f(acc[i][2]); o.w = silu_f(acc[i][3]);
        *(float4*)&B[(eb+i)*HS + 4*c4] = o;
    }
    __syncthreads();

    // vf layer 2 + residual add + store
    ACC_INIT(vb2)
    GEMM(B, HS, vw2, H)
    #pragma unroll
    for (int i = 0; i < 8; ++i) {
        const int node = n0 + eb + i;
        if (node < N_NODES) {
            const float4 a = *(const float4*)&A[(eb+i)*HS + 4*c4];
            float4 o;
            o.x = acc[i][0] + a.x; o.y = acc[i][1] + a.y;
            o.z = acc[i][2] + a.z; o.w = acc[i][3] + a.w;
            *(float4*)&out[(size_t)node*H + 4*c4] = o;
        }
    }

    // vn_pos = tile(pos,4) + agg_vec/cnt
    for (int flat = t; flat < MN*12; flat += 256) {
        const int e = flat / 12, m = flat % 12;
        const int node = n0 + e;
        if (node < N_NODES) {
            out[(size_t)N_NODES*H + (size_t)node*12 + m] =
                pos[node*3 + (m % 3)] + agg_vec[(size_t)node*12 + m] * invS[e];
        }
    }
}

extern "C" void kernel_launch(void* const* d_in, const int* in_sizes, int n_in,
                              void* d_out, int out_size, void* d_ws, size_t ws_size,
                              hipStream_t stream)
{
    const float* node_feat = (const float*)d_in[0];
    const float* node_pos  = (const float*)d_in[1];
    const int*   eidx      = (const int*)  d_in[2];
    const float* eattr     = (const float*)d_in[3];
    const float* fi_w1  = (const float*)d_in[4];
    const float* fi_b1  = (const float*)d_in[5];
    const float* fi_w2  = (const float*)d_in[6];
    const float* fi_b2  = (const float*)d_in[7];
    const float* msg_w1 = (const float*)d_in[8];
    const float* msg_b1 = (const float*)d_in[9];
    const float* msg_w2 = (const float*)d_in[10];
    const float* msg_b2 = (const float*)d_in[11];
    const float* co_w1  = (const float*)d_in[12];
    const float* co_b1  = (const float*)d_in[13];
    const float* co_w2  = (const float*)d_in[14];
    const float* co_b2  = (const float*)d_in[15];
    const float* vf_w1  = (const float*)d_in[16];
    const float* vf_b1  = (const float*)d_in[17];
    const float* vf_w2  = (const float*)d_in[18];
    const float* vf_b2  = (const float*)d_in[19];

    float* out     = (float*)d_out;
    float* agg_msg = (float*)d_ws;                        // [N,128]
    float* agg_vec = agg_msg + (size_t)N_NODES * H;       // [N,12]
    float* cntp    = agg_vec + (size_t)N_NODES * 12;      // [N]

    // ws is re-poisoned to 0xAA before every launch -> zero what we use
    hipMemsetAsync(d_ws, 0, (size_t)N_NODES * (H + 12 + 1) * sizeof(float), stream);

    edge_kernel<<<N_EDGES / ME, 256, 0, stream>>>(
        node_feat, node_pos, eidx, eattr,
        msg_w1, msg_b1, msg_w2, msg_b2,
        co_w1, co_b1, co_w2, co_b2,
        agg_msg, agg_vec, cntp);

    node_kernel<<<(N_NODES + MN - 1) / MN, 256, 0, stream>>>(
        node_feat, node_pos,
        fi_w1, fi_b1, fi_w2, fi_b2,
        vf_w1, vf_b1, vf_w2, vf_b2,
        agg_msg, agg_vec, cntp, out);
}

// Round 2
// 939.565 us; speedup vs baseline: 2.1642x; 2.1642x over previous
//
#include <hip/hip_runtime.h>
#include <math.h>

#define N_NODES 50000
#define N_EDGES 800000
#define H       128

typedef _Float16 f16x8 __attribute__((ext_vector_type(8)));
typedef _Float16 f16x4 __attribute__((ext_vector_type(4)));
typedef float    f32x4 __attribute__((ext_vector_type(4)));

#define KP1 320   // padded K for GEMM1 (292 -> 320)
#define KS1 10    // KP1/32
#define KS2 4     // 128/32

// LDS region byte offsets (inside one char array, 16B-aligned)
#define XOFF 0        // X tile  [64][320] f16 = 40960 B (dead after GEMM1)
#define MOFF 0        // msg     [64][128] f16 = 16384 B (reuses X region)
#define HOFF 40960    // h / h2  [64][128] f16 = 16384 B
#define XSTR 640      // X row stride bytes
#define HSTR 256      // h/msg row stride bytes
#define LDSB 57344

__device__ __forceinline__ float silu_f(float x) {
    return x / (1.0f + expf(-x));
}

// ---------------------------------------------------------------------------
// Weight prep: fp32 [K][128] -> f16 frag-packed [ct][ks][lane][8], K padded
// Element (ct,ks,lane,j) = W[ks*32 + (lane>>4)*8 + j][ct*16 + (lane&15)]
// ---------------------------------------------------------------------------
__global__ void pack_w(const float* __restrict__ W, int K, int KP,
                       _Float16* __restrict__ out) {
    const int idx = blockIdx.x * 256 + threadIdx.x;
    if (idx >= 128 * KP) return;
    const int j  = idx & 7;
    const int l  = (idx >> 3) & 63;
    const int rem = idx >> 9;            // ct*KS + ks
    const int KS = KP >> 5;
    const int ct = rem / KS, ks = rem % KS;
    const int k  = ks * 32 + (l >> 4) * 8 + j;
    const int c  = ct * 16 + (l & 15);
    const float w = (k < K) ? W[k * 128 + c] : 0.0f;
    out[idx] = (_Float16)w;
}

// swizzled LDS accessors: byte ^= (row&7)<<4 breaks the 0-mod-128B row stride
__device__ __forceinline__ f16x8 ld_frag(const char* sp, int off, int row,
                                         int strideB, int kb) {
    const int byte = (off + row * strideB + kb * 2) ^ ((row & 7) << 4);
    return *(const f16x8*)(sp + byte);
}
__device__ __forceinline__ void st_f16(char* sp, int off, int row, int col,
                                       _Float16 v) {
    const int byte = (off + row * HSTR + col * 2) ^ ((row & 7) << 4);
    *(_Float16*)(sp + byte) = v;
}
__device__ __forceinline__ float ld_f16(const char* sp, int off, int row, int col) {
    const int byte = (off + row * HSTR + col * 2) ^ ((row & 7) << 4);
    return (float)*(const _Float16*)(sp + byte);
}

// one wave: 64 rows x 16 cols (col tile = wave id), K = KS*32, A from LDS
#define MFMA_GEMM(OFF, STRIDEB, KS, WPK)                                      \
    {                                                                         \
        _Pragma("unroll")                                                     \
        for (int ks = 0; ks < (KS); ++ks) {                                   \
            const f16x8 b = *(const f16x8*)&(WPK)[(((w * (KS)) + ks) * 64 + lane) * 8]; \
            _Pragma("unroll")                                                 \
            for (int rt = 0; rt < 4; ++rt) {                                  \
                const f16x8 a = ld_frag(sp, (OFF), rt * 16 + lr, (STRIDEB),   \
                                        ks * 32 + lk * 8);                    \
                acc[rt] = __builtin_amdgcn_mfma_f32_16x16x32_f16(a, b, acc[rt], 0, 0, 0); \
            }                                                                 \
        }                                                                     \
    }

// epilogue: C row = rt*16 + lk*4 + i, col = w*16 + lr (verified C/D layout)
#define EPILOGUE(OFF, BIAS, ACT)                                              \
    {                                                                         \
        const int col = w * 16 + lr;                                          \
        const float bv = (BIAS)[col];                                         \
        _Pragma("unroll")                                                     \
        for (int rt = 0; rt < 4; ++rt) {                                      \
            _Pragma("unroll")                                                 \
            for (int i = 0; i < 4; ++i) {                                     \
                float v = acc[rt][i] + bv;                                    \
                if (ACT) v = silu_f(v);                                       \
                st_f16(sp, (OFF), rt * 16 + lk * 4 + i, col, (_Float16)v);    \
            }                                                                 \
        }                                                                     \
    }

// ---------------------------------------------------------------------------
// Edge kernel: gather -> 3 MFMA GEMMs -> VALU coff -> atomic segment sums
// ---------------------------------------------------------------------------
__global__ __launch_bounds__(512, 4) void edge_kernel(
    const float* __restrict__ feat, const float* __restrict__ pos,
    const int*   __restrict__ eidx, const float* __restrict__ eattr,
    const _Float16* __restrict__ wpk1, const float* __restrict__ mb1,
    const _Float16* __restrict__ wpk2, const float* __restrict__ mb2,
    const _Float16* __restrict__ wpk3, const float* __restrict__ cb1,
    const float* __restrict__ cw2, const float* __restrict__ cb2,
    float* __restrict__ agg_msg, float* __restrict__ agg_vec,
    float* __restrict__ cnt)
{
    __shared__ alignas(16) char Sb[LDSB];
    __shared__ float unitS[64][3];
    __shared__ float coffS[64][4];
    __shared__ int   rowS[64];
    __shared__ int   colS[64];
    char* sp = (char*)Sb;

    const int t    = threadIdx.x;
    const int lane = t & 63;
    const int w    = t >> 6;          // wave id = col tile (16 cols each)
    const int lr   = lane & 15;
    const int lk   = lane >> 4;
    const int e0   = blockIdx.x * 64;

    // --- phase 0: geometry ---
    float dsq_t = 0.0f;
    if (t < 64) {
        const int r = eidx[e0 + t];
        const int c = eidx[N_EDGES + e0 + t];
        rowS[t] = r; colS[t] = c;
        const float dx = pos[r*3+0] - pos[c*3+0];
        const float dy = pos[r*3+1] - pos[c*3+1];
        const float dz = pos[r*3+2] - pos[c*3+2];
        const float dsq = dx*dx + dy*dy + dz*dz;
        const float inv = 1.0f / fmaxf(sqrtf(dsq), 1e-8f);
        unitS[t][0] = dx * inv;
        unitS[t][1] = dy * inv;
        unitS[t][2] = dz * inv;
        dsq_t = dsq;
    }
    // zero-pad region k in [296,320) while waiting (disjoint from dsq chunk)
    if (t < 256) {
        const int e = t >> 2, c = t & 3;
        if (c < 3) {
            const int byte = (XOFF + e * XSTR + (296 + c * 8) * 2) ^ ((e & 7) << 4);
            *(f16x8*)(sp + byte) = (f16x8)(_Float16)0.0f;
        }
    }
    if (t < 64) {   // dsq at k=288..291, zeros 292..295 (one 16B chunk)
        f16x8 dv = (f16x8)(_Float16)0.0f;
        const _Float16 dh = (_Float16)dsq_t;
        dv[0] = dh; dv[1] = dh; dv[2] = dh; dv[3] = dh;
        const int byte = (XOFF + t * XSTR + 288 * 2) ^ ((t & 7) << 4);
        *(f16x8*)(sp + byte) = dv;
    }
    __syncthreads();

    // --- phase 1: build X tile [feat[row] | feat[col] | eattr | dsq,pad] ---
    const float4* feat4 = (const float4*)feat;
    #pragma unroll
    for (int s = 0; s < 8; ++s) {
        const int flat = t + 512 * s;          // 0..4095
        const int e = flat >> 6, rest = flat & 63;
        const int side = rest >> 5, q = rest & 31;
        const int node = side ? colS[e] : rowS[e];
        const float4 v = feat4[(size_t)node * 32 + q];
        f16x4 o; o[0]=(_Float16)v.x; o[1]=(_Float16)v.y; o[2]=(_Float16)v.z; o[3]=(_Float16)v.w;
        const int k0 = side * 128 + q * 4;
        const int byte = (XOFF + e * XSTR + k0 * 2) ^ ((e & 7) << 4);
        *(f16x4*)(sp + byte) = o;
    }
    {   // edge_attr: k in [256,288)
        const int e = t >> 3, q = t & 7;
        const float4 v = ((const float4*)eattr)[(size_t)(e0 + e) * 8 + q];
        f16x4 o; o[0]=(_Float16)v.x; o[1]=(_Float16)v.y; o[2]=(_Float16)v.z; o[3]=(_Float16)v.w;
        const int byte = (XOFF + e * XSTR + (256 + q * 4) * 2) ^ ((e & 7) << 4);
        *(f16x4*)(sp + byte) = o;
    }
    __syncthreads();

    f32x4 acc[4];

    // ---- GEMM1: h = silu(X @ mw1 + mb1) ----
    #pragma unroll
    for (int rt = 0; rt < 4; ++rt) acc[rt] = (f32x4)0.0f;
    MFMA_GEMM(XOFF, XSTR, KS1, wpk1)
    EPILOGUE(HOFF, mb1, 1)
    __syncthreads();

    // ---- GEMM2: msg = h @ mw2 + mb2 (msg region reuses dead X region) ----
    #pragma unroll
    for (int rt = 0; rt < 4; ++rt) acc[rt] = (f32x4)0.0f;
    MFMA_GEMM(HOFF, HSTR, KS2, wpk2)
    EPILOGUE(MOFF, mb2, 0)
    __syncthreads();

    // ---- GEMM3: h2 = silu(msg @ cw1 + cb1), overwrite h region ----
    #pragma unroll
    for (int rt = 0; rt < 4; ++rt) acc[rt] = (f32x4)0.0f;
    MFMA_GEMM(MOFF, HSTR, KS2, wpk3)
    EPILOGUE(HOFF, cb1, 1)
    __syncthreads();

    // ---- GEMM4: coff = h2 @ cw2 + cb2 (128 -> 4, VALU) ----
    if (t < 256) {
        const int e = t >> 2, c = t & 3;
        float a = cb2[c];
        for (int k = 0; k < 128; ++k)
            a = fmaf(ld_f16(sp, HOFF, e, k), cw2[k * 4 + c], a);
        coffS[e][c] = a;
    }
    __syncthreads();

    // ---- atomic segment sums ----
    #pragma unroll
    for (int s = 0; s < 16; ++s) {
        const int flat = t + 512 * s;          // 0..8191
        const int e = flat >> 7, c = flat & 127;
        atomicAdd(&agg_msg[(size_t)rowS[e] * H + c], ld_f16(sp, MOFF, e, c));
    }
    for (int flat = t; flat < 64 * 12; flat += 512) {
        const int e = flat / 12, m = flat % 12;
        atomicAdd(&agg_vec[(size_t)rowS[e] * 12 + m],
                  coffS[e][m / 3] * unitS[e][m % 3]);
    }
    if (t < 64) atomicAdd(&cnt[rowS[t]], 1.0f);
}

// ---------------------------------------------------------------------------
// Node kernel (fp32 VALU, unchanged from round 0 — proven correct)
// ---------------------------------------------------------------------------
#define MN  64
#define HS  132

#define FMA4(i, xs, wv)                              \
    acc[i][0] = fmaf((xs), (wv).x, acc[i][0]);       \
    acc[i][1] = fmaf((xs), (wv).y, acc[i][1]);       \
    acc[i][2] = fmaf((xs), (wv).z, acc[i][2]);       \
    acc[i][3] = fmaf((xs), (wv).w, acc[i][3]);

#define GEMM(SPTR, SSTRIDE, WPTR, KDIM)                                   \
    for (int k0 = 0; k0 < (KDIM); k0 += 4) {                              \
        const float4 wa = *(const float4*)&(WPTR)[(k0+0)*H + 4*c4];       \
        const float4 wb = *(const float4*)&(WPTR)[(k0+1)*H + 4*c4];       \
        const float4 wc = *(const float4*)&(WPTR)[(k0+2)*H + 4*c4];       \
        const float4 wd = *(const float4*)&(WPTR)[(k0+3)*H + 4*c4];       \
        _Pragma("unroll")                                                 \
        for (int i = 0; i < 8; ++i) {                                     \
            const float4 x = *(const float4*)&(SPTR)[(eb+i)*(SSTRIDE) + k0]; \
            FMA4(i, x.x, wa) FMA4(i, x.y, wb)                             \
            FMA4(i, x.z, wc) FMA4(i, x.w, wd)                             \
        }                                                                 \
    }

#define ACC_INIT(BPTR)                                                    \
    {                                                                     \
        const float4 bb = *(const float4*)&(BPTR)[4*c4];                  \
        _Pragma("unroll")                                                 \
        for (int i = 0; i < 8; ++i) {                                     \
            acc[i][0]=bb.x; acc[i][1]=bb.y; acc[i][2]=bb.z; acc[i][3]=bb.w; \
        }                                                                 \
    }

__global__ __launch_bounds__(256, 2) void node_kernel(
    const float* __restrict__ feat, const float* __restrict__ pos,
    const float* __restrict__ fw1, const float* __restrict__ fb1,
    const float* __restrict__ fw2, const float* __restrict__ fb2,
    const float* __restrict__ vw1, const float* __restrict__ vb1,
    const float* __restrict__ vw2, const float* __restrict__ vb2,
    const float* __restrict__ agg_msg, const float* __restrict__ agg_vec,
    const float* __restrict__ cnt, float* __restrict__ out)
{
    __shared__ float A[MN*HS];
    __shared__ float B[MN*HS];
    __shared__ float invS[MN];

    const int t  = threadIdx.x;
    const int n0 = blockIdx.x * MN;
    const int c4 = t & 31;
    const int eb = (t >> 5) * 8;

    const float4* feat4 = (const float4*)feat;
    #pragma unroll
    for (int s = 0; s < 8; ++s) {
        const int flat = t + 256*s;
        const int e = flat >> 5, q = flat & 31;
        const int node = n0 + e;
        float4 v = make_float4(0.f, 0.f, 0.f, 0.f);
        if (node < N_NODES) v = feat4[(size_t)node*32 + q];
        *(float4*)&A[e*HS + 4*q] = v;
    }
    if (t < MN) {
        const int node = n0 + t;
        const float c = (node < N_NODES) ? cnt[node] : 1.0f;
        invS[t] = 1.0f / fmaxf(c, 1.0f);
    }
    __syncthreads();

    float acc[8][4];

    ACC_INIT(fb1)
    GEMM(A, HS, fw1, H)
    #pragma unroll
    for (int i = 0; i < 8; ++i) {
        float4 o;
        o.x = silu_f(acc[i][0]); o.y = silu_f(acc[i][1]);
        o.z = silu_f(acc[i][2]); o.w = silu_f(acc[i][3]);
        *(float4*)&B[(eb+i)*HS + 4*c4] = o;
    }
    __syncthreads();

    ACC_INIT(fb2)
    GEMM(B, HS, fw2, H)
    #pragma unroll
    for (int i = 0; i < 8; ++i) {
        float4 o;
        o.x = silu_f(acc[i][0]); o.y = silu_f(acc[i][1]);
        o.z = silu_f(acc[i][2]); o.w = silu_f(acc[i][3]);
        *(float4*)&A[(eb+i)*HS + 4*c4] = o;
    }
    __syncthreads();

    const float4* agg4 = (const float4*)agg_msg;
    #pragma unroll
    for (int s = 0; s < 8; ++s) {
        const int flat = t + 256*s;
        const int e = flat >> 5, q = flat & 31;
        const int node = n0 + e;
        float4 v = make_float4(0.f, 0.f, 0.f, 0.f);
        if (node < N_NODES) v = agg4[(size_t)node*32 + q];
        const float iv = invS[e];
        v.x *= iv; v.y *= iv; v.z *= iv; v.w *= iv;
        *(float4*)&B[e*HS + 4*q] = v;
    }
    __syncthreads();

    ACC_INIT(vb1)
    GEMM(B, HS, vw1, H)
    __syncthreads();
    #pragma unroll
    for (int i = 0; i < 8; ++i) {
        float4 o;
        o.x = silu_f(acc[i][0]); o.y = silu_f(acc[i][1]);
        o.z = silu_f(acc[i][2]); o.w = silu_f(acc[i][3]);
        *(float4*)&B[(eb+i)*HS + 4*c4] = o;
    }
    __syncthreads();

    ACC_INIT(vb2)
    GEMM(B, HS, vw2, H)
    #pragma unroll
    for (int i = 0; i < 8; ++i) {
        const int node = n0 + eb + i;
        if (node < N_NODES) {
            const float4 a = *(const float4*)&A[(eb+i)*HS + 4*c4];
            float4 o;
            o.x = acc[i][0] + a.x; o.y = acc[i][1] + a.y;
            o.z = acc[i][2] + a.z; o.w = acc[i][3] + a.w;
            *(float4*)&out[(size_t)node*H + 4*c4] = o;
        }
    }

    for (int flat = t; flat < MN*12; flat += 256) {
        const int e = flat / 12, m = flat % 12;
        const int node = n0 + e;
        if (node < N_NODES) {
            out[(size_t)N_NODES*H + (size_t)node*12 + m] =
                pos[node*3 + (m % 3)] + agg_vec[(size_t)node*12 + m] * invS[e];
        }
    }
}

extern "C" void kernel_launch(void* const* d_in, const int* in_sizes, int n_in,
                              void* d_out, int out_size, void* d_ws, size_t ws_size,
                              hipStream_t stream)
{
    const float* node_feat = (const float*)d_in[0];
    const float* node_pos  = (const float*)d_in[1];
    const int*   eidx      = (const int*)  d_in[2];
    const float* eattr     = (const float*)d_in[3];
    const float* fi_w1  = (const float*)d_in[4];
    const float* fi_b1  = (const float*)d_in[5];
    const float* fi_w2  = (const float*)d_in[6];
    const float* fi_b2  = (const float*)d_in[7];
    const float* msg_w1 = (const float*)d_in[8];
    const float* msg_b1 = (const float*)d_in[9];
    const float* msg_w2 = (const float*)d_in[10];
    const float* msg_b2 = (const float*)d_in[11];
    const float* co_w1  = (const float*)d_in[12];
    const float* co_b1  = (const float*)d_in[13];
    const float* co_w2  = (const float*)d_in[14];
    const float* co_b2  = (const float*)d_in[15];
    const float* vf_w1  = (const float*)d_in[16];
    const float* vf_b1  = (const float*)d_in[17];
    const float* vf_w2  = (const float*)d_in[18];
    const float* vf_b2  = (const float*)d_in[19];

    float* out     = (float*)d_out;
    float* agg_msg = (float*)d_ws;                        // [N,128]
    float* agg_vec = agg_msg + (size_t)N_NODES * H;       // [N,12]
    float* cntp    = agg_vec + (size_t)N_NODES * 12;      // [N]
    _Float16* wpk1 = (_Float16*)(cntp + N_NODES);         // 128*320 f16
    _Float16* wpk2 = wpk1 + 128 * KP1;                    // 128*128 f16
    _Float16* wpk3 = wpk2 + 128 * 128;                    // 128*128 f16

    hipMemsetAsync(d_ws, 0, (size_t)N_NODES * (H + 12 + 1) * sizeof(float), stream);
    pack_w<<<(128 * KP1 + 255) / 256, 256, 0, stream>>>(msg_w1, 292, KP1, wpk1);
    pack_w<<<(128 * 128 + 255) / 256, 256, 0, stream>>>(msg_w2, 128, 128, wpk2);
    pack_w<<<(128 * 128 + 255) / 256, 256, 0, stream>>>(co_w1, 128, 128, wpk3);

    edge_kernel<<<N_EDGES / 64, 512, 0, stream>>>(
        node_feat, node_pos, eidx, eattr,
        wpk1, msg_b1, wpk2, msg_b2, wpk3, co_b1, co_w2, co_b2,
        agg_msg, agg_vec, cntp);

    node_kernel<<<(N_NODES + MN - 1) / MN, 256, 0, stream>>>(
        node_feat, node_pos,
        fi_w1, fi_b1, fi_w2, fi_b2,
        vf_w1, vf_b1, vf_w2, vf_b2,
        agg_msg, agg_vec, cntp, out);
}

// Round 3
// 644.345 us; speedup vs baseline: 3.1558x; 1.4582x over previous
//
#include <hip/hip_runtime.h>
#include <math.h>

#define N_NODES 50000
#define NTOT    50176   // 196*256, padded node count for the scan
#define NB      196
#define N_EDGES 800000
#define H       128

typedef _Float16 f16x8 __attribute__((ext_vector_type(8)));
typedef _Float16 f16x4 __attribute__((ext_vector_type(4)));
typedef float    f32x4 __attribute__((ext_vector_type(4)));

#define KP1 320   // padded K for GEMM1 (292 -> 320)
#define KS1 10    // KP1/32
#define KS2 4     // 128/32

// Edge-kernel LDS regions (byte offsets in one char array)
#define XOFF 0        // X tile  [64][320] f16 = 40960 B (dead after GEMM1)
#define MOFF 0        // msg     [64][128] f16 (reuses X region)
#define HOFF 40960    // h / h2  [64][128] f16
#define XSTR 640
#define HSTR 256
#define LDSB 57344

__device__ __forceinline__ float fast_rcp(float x) {
#if __has_builtin(__builtin_amdgcn_rcpf)
    return __builtin_amdgcn_rcpf(x);
#else
    return 1.0f / x;
#endif
}
__device__ __forceinline__ float fast_exp2(float x) {
#if __has_builtin(__builtin_amdgcn_exp2f)
    return __builtin_amdgcn_exp2f(x);
#else
    return exp2f(x);
#endif
}
__device__ __forceinline__ float silu_f(float x) {
    // x * 1/(1+exp(-x)); rcp/exp2 approx err ~1e-6 << f16 storage eps
    return x * fast_rcp(1.0f + fast_exp2(-1.44269504089f * x));
}

// ---------------------------------------------------------------------------
// Weight prep: fp32 [K][NCOL] -> f16 frag-packed [ct][ks][lane][8]
// element (ct,ks,l,j) = W[ks*32+(l>>4)*8+j][ct*16+(l&15)], zero-padded
// ---------------------------------------------------------------------------
__global__ void pack_w(const float* __restrict__ W, int K, int KP, int NCOL,
                       int CT, _Float16* __restrict__ out) {
    const int idx = blockIdx.x * 256 + threadIdx.x;
    const int KS = KP >> 5;
    if (idx >= CT * 16 * KP) return;
    const int j = idx & 7, l = (idx >> 3) & 63, rem = idx >> 9;
    const int ct = rem / KS, ks = rem % KS;
    const int k = ks * 32 + (l >> 4) * 8 + j;
    const int c = ct * 16 + (l & 15);
    out[idx] = (_Float16)((k < K && c < NCOL) ? W[k * NCOL + c] : 0.0f);
}

// ---------------------------------------------------------------------------
// Counting sort: hist -> 2-level exclusive scan -> scatter (perm)
// ---------------------------------------------------------------------------
__global__ void k_hist(const int* __restrict__ eidx, int* __restrict__ cnt) {
    const int e = blockIdx.x * 256 + threadIdx.x;
    atomicAdd(&cnt[eidx[e]], 1);
}

__global__ void k_scan1(const int* __restrict__ cnt, int* __restrict__ offs,
                        int* __restrict__ bsum) {
    __shared__ int sd[256];
    const int t = threadIdx.x;
    const int idx = blockIdx.x * 256 + t;
    const int v = cnt[idx];
    sd[t] = v;
    __syncthreads();
    for (int off = 1; off < 256; off <<= 1) {
        int x = (t >= off) ? sd[t - off] : 0;
        __syncthreads();
        sd[t] += x;
        __syncthreads();
    }
    offs[idx] = sd[t] - v;                     // block-local exclusive
    if (t == 255) bsum[blockIdx.x] = sd[255];
}

__global__ void k_scan2(int* __restrict__ bsum) {
    __shared__ int sd[256];
    const int t = threadIdx.x;
    const int v = (t < NB) ? bsum[t] : 0;
    sd[t] = v;
    __syncthreads();
    for (int off = 1; off < 256; off <<= 1) {
        int x = (t >= off) ? sd[t - off] : 0;
        __syncthreads();
        sd[t] += x;
        __syncthreads();
    }
    if (t < NB) bsum[t] = sd[t] - v;           // exclusive block offsets
}

__global__ void k_addcur(int* __restrict__ offs, const int* __restrict__ bsum,
                         int* __restrict__ cursor) {
    const int idx = blockIdx.x * 256 + threadIdx.x;
    const int v = offs[idx] + bsum[blockIdx.x];
    offs[idx] = v;
    cursor[idx] = v;
}

__global__ void k_scatter(const int* __restrict__ eidx, int* __restrict__ cursor,
                          int* __restrict__ perm) {
    const int e = blockIdx.x * 256 + threadIdx.x;
    const int r = eidx[e];
    const int p = atomicAdd(&cursor[r], 1);
    perm[p] = e;
}

// ---------------------------------------------------------------------------
// swizzled LDS accessors (byte ^= (row&7)<<4 kills 128B-stride conflicts)
// ---------------------------------------------------------------------------
__device__ __forceinline__ f16x8 ld_frag(const char* sp, int off, int row,
                                         int strideB, int kb) {
    const int byte = (off + row * strideB + kb * 2) ^ ((row & 7) << 4);
    return *(const f16x8*)(sp + byte);
}
__device__ __forceinline__ void st_f16(char* sp, int off, int row, int col,
                                       _Float16 v) {
    const int byte = (off + row * HSTR + col * 2) ^ ((row & 7) << 4);
    *(_Float16*)(sp + byte) = v;
}
__device__ __forceinline__ float ld_f16(const char* sp, int off, int row, int col) {
    const int byte = (off + row * HSTR + col * 2) ^ ((row & 7) << 4);
    return (float)*(const _Float16*)(sp + byte);
}

// one wave: 64 rows x 16 cols (col tile = wave id w), A from LDS, B packed
#define MFMA_GEMM(OFF, STRIDEB, KS, WPK)                                      \
    {                                                                         \
        _Pragma("unroll")                                                     \
        for (int ks = 0; ks < (KS); ++ks) {                                   \
            const f16x8 b = *(const f16x8*)&(WPK)[(((w * (KS)) + ks) * 64 + lane) * 8]; \
            _Pragma("unroll")                                                 \
            for (int rt = 0; rt < 4; ++rt) {                                  \
                const f16x8 a = ld_frag(sp, (OFF), rt * 16 + lr, (STRIDEB),   \
                                        ks * 32 + lk * 8);                    \
                acc[rt] = __builtin_amdgcn_mfma_f32_16x16x32_f16(a, b, acc[rt], 0, 0, 0); \
            }                                                                 \
        }                                                                     \
    }

#define ACC_ZERO { _Pragma("unroll") for (int rt = 0; rt < 4; ++rt) acc[rt] = (f32x4)0.0f; }

// epilogue: C row = rt*16 + lk*4 + i, col = w*16 + lr
#define EPILOGUE(OFF, BIAS, ACT)                                              \
    {                                                                         \
        const int col = w * 16 + lr;                                          \
        const float bv = (BIAS)[col];                                         \
        _Pragma("unroll")                                                     \
        for (int rt = 0; rt < 4; ++rt) {                                      \
            _Pragma("unroll")                                                 \
            for (int i = 0; i < 4; ++i) {                                     \
                float v = acc[rt][i] + bv;                                    \
                if (ACT) v = silu_f(v);                                       \
                st_f16(sp, (OFF), rt * 16 + lk * 4 + i, col, (_Float16)v);    \
            }                                                                 \
        }                                                                     \
    }

// ---------------------------------------------------------------------------
// Edge kernel (consumes perm-sorted edges): gather -> 4 MFMA GEMMs ->
// run-compressed atomic segment sums
// ---------------------------------------------------------------------------
__global__ __launch_bounds__(512, 4) void edge_kernel(
    const float* __restrict__ feat, const float* __restrict__ pos,
    const int*   __restrict__ eidx, const float* __restrict__ eattr,
    const int*   __restrict__ perm,
    const _Float16* __restrict__ wpk1, const float* __restrict__ mb1,
    const _Float16* __restrict__ wpk2, const float* __restrict__ mb2,
    const _Float16* __restrict__ wpk3, const float* __restrict__ cb1,
    const _Float16* __restrict__ wpk4, const float* __restrict__ cb2,
    float* __restrict__ agg_msg, float* __restrict__ agg_vec)
{
    __shared__ alignas(16) char Sb[LDSB];
    __shared__ float unitS[64][3];
    __shared__ float coffS[64][4];
    __shared__ int   rowS[64];
    __shared__ int   colS[64];
    __shared__ int   peS[64];
    __shared__ int   runListS[65];
    __shared__ int   nRunsS;
    char* sp = (char*)Sb;

    const int t    = threadIdx.x;
    const int lane = t & 63;
    const int w    = t >> 6;
    const int lr   = lane & 15;
    const int lk   = lane >> 4;
    const int e0   = blockIdx.x * 64;

    // --- phase 0: geometry + run detection (wave 0) ---
    if (t < 64) {
        const int pe = perm[e0 + t];
        const int r = eidx[pe];
        const int c = eidx[N_EDGES + pe];
        peS[t] = pe; rowS[t] = r; colS[t] = c;
        const float dx = pos[r*3+0] - pos[c*3+0];
        const float dy = pos[r*3+1] - pos[c*3+1];
        const float dz = pos[r*3+2] - pos[c*3+2];
        const float dsq = dx*dx + dy*dy + dz*dz;
        const float inv = 1.0f / fmaxf(sqrtf(dsq), 1e-8f);
        unitS[t][0] = dx * inv;
        unitS[t][1] = dy * inv;
        unitS[t][2] = dz * inv;
        // sorted rows -> contiguous runs; find run starts via shuffle+ballot
        const int prev = __shfl_up(r, 1);
        const bool isStart = (t == 0) || (prev != r);
        const unsigned long long mask = __ballot(isStart);
        const int nR = __popcll(mask);
        if (isStart) runListS[__popcll(mask & ((1ull << t) - 1))] = t;
        if (t == 0)  nRunsS = nR;
        if (t == 63) runListS[nR] = 64;           // sentinel
        // dsq at k=288..295 (one 16B chunk: 4x dsq + 4 zeros)
        f16x8 dv = (f16x8)(_Float16)0.0f;
        const _Float16 dh = (_Float16)dsq;
        dv[0] = dh; dv[1] = dh; dv[2] = dh; dv[3] = dh;
        const int byte = (XOFF + t * XSTR + 288 * 2) ^ ((t & 7) << 4);
        *(f16x8*)(sp + byte) = dv;
    }
    // zero-pad k in [296,320)
    if (t < 256) {
        const int e = t >> 2, c = t & 3;
        if (c < 3) {
            const int byte = (XOFF + e * XSTR + (296 + c * 8) * 2) ^ ((e & 7) << 4);
            *(f16x8*)(sp + byte) = (f16x8)(_Float16)0.0f;
        }
    }
    __syncthreads();

    // --- phase 1: build X tile [feat[row] | feat[col] | eattr | dsq,pad] ---
    const float4* feat4 = (const float4*)feat;
    #pragma unroll
    for (int s = 0; s < 8; ++s) {
        const int flat = t + 512 * s;          // 0..4095
        const int e = flat >> 6, rest = flat & 63;
        const int side = rest >> 5, q = rest & 31;
        const int node = side ? colS[e] : rowS[e];
        const float4 v = feat4[(size_t)node * 32 + q];
        f16x4 o; o[0]=(_Float16)v.x; o[1]=(_Float16)v.y; o[2]=(_Float16)v.z; o[3]=(_Float16)v.w;
        const int byte = (XOFF + e * XSTR + (side * 128 + q * 4) * 2) ^ ((e & 7) << 4);
        *(f16x4*)(sp + byte) = o;
    }
    {   // edge_attr rows via perm
        const int e = t >> 3, q = t & 7;
        const float4 v = ((const float4*)eattr)[(size_t)peS[e] * 8 + q];
        f16x4 o; o[0]=(_Float16)v.x; o[1]=(_Float16)v.y; o[2]=(_Float16)v.z; o[3]=(_Float16)v.w;
        const int byte = (XOFF + e * XSTR + (256 + q * 4) * 2) ^ ((e & 7) << 4);
        *(f16x4*)(sp + byte) = o;
    }
    __syncthreads();

    f32x4 acc[4];

    // ---- GEMM1: h = silu(X @ mw1 + mb1) ----
    ACC_ZERO
    MFMA_GEMM(XOFF, XSTR, KS1, wpk1)
    EPILOGUE(HOFF, mb1, 1)
    __syncthreads();

    // ---- GEMM2: msg = h @ mw2 + mb2 (msg overwrites dead X region) ----
    ACC_ZERO
    MFMA_GEMM(HOFF, HSTR, KS2, wpk2)
    EPILOGUE(MOFF, mb2, 0)
    __syncthreads();

    // ---- GEMM3: h2 = silu(msg @ cw1 + cb1) ----
    ACC_ZERO
    MFMA_GEMM(MOFF, HSTR, KS2, wpk3)
    EPILOGUE(HOFF, cb1, 1)
    __syncthreads();

    // ---- GEMM4 (waves 0-3): coff = h2 @ cw2 + cb2, 128->4 via MFMA ----
    if (w < 4) {
        f32x4 a4 = (f32x4)0.0f;
        #pragma unroll
        for (int ks = 0; ks < 4; ++ks) {
            const f16x8 b = *(const f16x8*)&wpk4[(ks * 64 + lane) * 8];
            const f16x8 a = ld_frag(sp, HOFF, w * 16 + lr, HSTR, ks * 32 + lk * 8);
            a4 = __builtin_amdgcn_mfma_f32_16x16x32_f16(a, b, a4, 0, 0, 0);
        }
        if (lr < 4) {
            #pragma unroll
            for (int i = 0; i < 4; ++i)
                coffS[w * 16 + lk * 4 + i][lr] = a4[i] + cb2[lr];
        }
    }

    // ---- run-compressed msg aggregation (waves 4-7 start immediately) ----
    const int nR = nRunsS;
    for (int it = t; it < nR * 128; it += 512) {
        const int run = it >> 7, c = it & 127;
        const int s = runListS[run], epos = runListS[run + 1];
        float a = 0.0f;
        for (int k = s; k < epos; ++k) a += ld_f16(sp, MOFF, k, c);
        atomicAdd(&agg_msg[(size_t)rowS[s] * H + c], a);
    }
    __syncthreads();   // coffS ready

    // ---- run-compressed vec aggregation ----
    for (int it = t; it < nR * 12; it += 512) {
        const int run = it / 12, m = it % 12;
        const int s = runListS[run], epos = runListS[run + 1];
        float a = 0.0f;
        for (int k = s; k < epos; ++k) a += coffS[k][m / 3] * unitS[k][m % 3];
        atomicAdd(&agg_vec[(size_t)rowS[s] * 12 + m], a);
    }
}

// ---------------------------------------------------------------------------
// Node kernel (MFMA): vn_feat = siluMLP(feat) + MLP(agg_mean); vn_pos
// ---------------------------------------------------------------------------
#define AOFF 0
#define BOFF 16384
#define NLDS 32768

__global__ __launch_bounds__(512, 4) void node_kernel(
    const float* __restrict__ feat, const float* __restrict__ pos,
    const _Float16* __restrict__ wf1, const float* __restrict__ fb1,
    const _Float16* __restrict__ wf2, const float* __restrict__ fb2,
    const _Float16* __restrict__ wv1, const float* __restrict__ vb1,
    const _Float16* __restrict__ wv2, const float* __restrict__ vb2,
    const float* __restrict__ agg_msg, const float* __restrict__ agg_vec,
    const int* __restrict__ cnt_i, float* __restrict__ out)
{
    __shared__ alignas(16) char Sb[NLDS];
    __shared__ float invS[64];
    char* sp = (char*)Sb;

    const int t    = threadIdx.x;
    const int lane = t & 63;
    const int w    = t >> 6;
    const int lr   = lane & 15;
    const int lk   = lane >> 4;
    const int n0   = blockIdx.x * 64;

    // --- phase A: feat -> Xa (f16), invS ---
    const float4* feat4 = (const float4*)feat;
    #pragma unroll
    for (int s = 0; s < 4; ++s) {
        const int flat = t + 512 * s;          // 0..2047
        const int e = flat >> 5, q = flat & 31;
        const int node = n0 + e;
        float4 v = make_float4(0.f, 0.f, 0.f, 0.f);
        if (node < N_NODES) v = feat4[(size_t)node * 32 + q];
        f16x4 o; o[0]=(_Float16)v.x; o[1]=(_Float16)v.y; o[2]=(_Float16)v.z; o[3]=(_Float16)v.w;
        const int byte = (AOFF + e * HSTR + q * 8) ^ ((e & 7) << 4);
        *(f16x4*)(sp + byte) = o;
    }
    if (t < 64) {
        const int node = n0 + t;
        const float c = (node < N_NODES) ? (float)cnt_i[node] : 1.0f;
        invS[t] = fast_rcp(fmaxf(c, 1.0f));
    }
    __syncthreads();

    f32x4 acc[4];
    float resid[4][4];

    // fi1: Xb = silu(Xa @ fw1 + fb1)
    ACC_ZERO
    MFMA_GEMM(AOFF, HSTR, KS2, wf1)
    EPILOGUE(BOFF, fb1, 1)
    __syncthreads();

    // fi2: resid = silu(Xb @ fw2 + fb2) kept in registers
    ACC_ZERO
    MFMA_GEMM(BOFF, HSTR, KS2, wf2)
    {
        const float bv = fb2[w * 16 + lr];
        #pragma unroll
        for (int rt = 0; rt < 4; ++rt)
            #pragma unroll
            for (int i = 0; i < 4; ++i)
                resid[rt][i] = silu_f(acc[rt][i] + bv);
    }
    __syncthreads();

    // --- phase B: agg_msg mean -> Xa (f16) ---
    const float4* agg4 = (const float4*)agg_msg;
    #pragma unroll
    for (int s = 0; s < 4; ++s) {
        const int flat = t + 512 * s;
        const int e = flat >> 5, q = flat & 31;
        const int node = n0 + e;
        float4 v = make_float4(0.f, 0.f, 0.f, 0.f);
        if (node < N_NODES) v = agg4[(size_t)node * 32 + q];
        const float iv = invS[e];
        f16x4 o; o[0]=(_Float16)(v.x*iv); o[1]=(_Float16)(v.y*iv);
        o[2]=(_Float16)(v.z*iv); o[3]=(_Float16)(v.w*iv);
        const int byte = (AOFF + e * HSTR + q * 8) ^ ((e & 7) << 4);
        *(f16x4*)(sp + byte) = o;
    }
    __syncthreads();

    // vf1: Xb = silu(Xa @ vw1 + vb1)
    ACC_ZERO
    MFMA_GEMM(AOFF, HSTR, KS2, wv1)
    EPILOGUE(BOFF, vb1, 1)
    __syncthreads();

    // vf2 + residual -> out
    ACC_ZERO
    MFMA_GEMM(BOFF, HSTR, KS2, wv2)
    {
        const int col = w * 16 + lr;
        const float bv = vb2[col];
        #pragma unroll
        for (int rt = 0; rt < 4; ++rt) {
            #pragma unroll
            for (int i = 0; i < 4; ++i) {
                const int node = n0 + rt * 16 + lk * 4 + i;
                if (node < N_NODES)
                    out[(size_t)node * H + col] = acc[rt][i] + bv + resid[rt][i];
            }
        }
    }

    // vn_pos = tile(pos,4) + agg_vec * inv
    for (int fl = t; fl < 64 * 12; fl += 512) {
        const int e = fl / 12, m = fl % 12;
        const int node = n0 + e;
        if (node < N_NODES)
            out[(size_t)N_NODES * H + (size_t)node * 12 + m] =
                pos[node * 3 + (m % 3)] + agg_vec[(size_t)node * 12 + m] * invS[e];
    }
}

extern "C" void kernel_launch(void* const* d_in, const int* in_sizes, int n_in,
                              void* d_out, int out_size, void* d_ws, size_t ws_size,
                              hipStream_t stream)
{
    const float* node_feat = (const float*)d_in[0];
    const float* node_pos  = (const float*)d_in[1];
    const int*   eidx      = (const int*)  d_in[2];
    const float* eattr     = (const float*)d_in[3];
    const float* fi_w1  = (const float*)d_in[4];
    const float* fi_b1  = (const float*)d_in[5];
    const float* fi_w2  = (const float*)d_in[6];
    const float* fi_b2  = (const float*)d_in[7];
    const float* msg_w1 = (const float*)d_in[8];
    const float* msg_b1 = (const float*)d_in[9];
    const float* msg_w2 = (const float*)d_in[10];
    const float* msg_b2 = (const float*)d_in[11];
    const float* co_w1  = (const float*)d_in[12];
    const float* co_b1  = (const float*)d_in[13];
    const float* co_w2  = (const float*)d_in[14];
    const float* co_b2  = (const float*)d_in[15];
    const float* vf_w1  = (const float*)d_in[16];
    const float* vf_b1  = (const float*)d_in[17];
    const float* vf_w2  = (const float*)d_in[18];
    const float* vf_b2  = (const float*)d_in[19];

    float* out     = (float*)d_out;
    float* agg_msg = (float*)d_ws;                          // [N,128] f32
    float* agg_vec = agg_msg + (size_t)N_NODES * H;         // [N,12]  f32
    int*   cnt_i   = (int*)(agg_vec + (size_t)N_NODES * 12);// [NTOT]
    int*   offs    = cnt_i + NTOT;                          // [NTOT]
    int*   cursor  = offs + NTOT;                           // [NTOT]
    int*   bsum    = cursor + NTOT;                         // [256]
    int*   perm    = bsum + 256;                            // [E]
    _Float16* wpk1 = (_Float16*)(perm + N_EDGES);           // 128*320
    _Float16* wpk2 = wpk1 + 128 * KP1;                      // 128*128
    _Float16* wpk3 = wpk2 + 128 * 128;                      // 128*128
    _Float16* wpk4 = wpk3 + 128 * 128;                      // 16*128
    _Float16* wpkF1 = wpk4 + 16 * 128;
    _Float16* wpkF2 = wpkF1 + 128 * 128;
    _Float16* wpkV1 = wpkF2 + 128 * 128;
    _Float16* wpkV2 = wpkV1 + 128 * 128;

    // zero agg_msg + agg_vec + cnt_i (contiguous)
    hipMemsetAsync(d_ws, 0,
                   ((size_t)N_NODES * (H + 12) + NTOT) * sizeof(float), stream);

    // weight packing (tiny)
    pack_w<<<(8 * 16 * KP1 + 255) / 256, 256, 0, stream>>>(msg_w1, 292, KP1, 128, 8, wpk1);
    pack_w<<<(8 * 16 * 128 + 255) / 256, 256, 0, stream>>>(msg_w2, 128, 128, 128, 8, wpk2);
    pack_w<<<(8 * 16 * 128 + 255) / 256, 256, 0, stream>>>(co_w1, 128, 128, 128, 8, wpk3);
    pack_w<<<(1 * 16 * 128 + 255) / 256, 256, 0, stream>>>(co_w2, 128, 128, 4, 1, wpk4);
    pack_w<<<(8 * 16 * 128 + 255) / 256, 256, 0, stream>>>(fi_w1, 128, 128, 128, 8, wpkF1);
    pack_w<<<(8 * 16 * 128 + 255) / 256, 256, 0, stream>>>(fi_w2, 128, 128, 128, 8, wpkF2);
    pack_w<<<(8 * 16 * 128 + 255) / 256, 256, 0, stream>>>(vf_w1, 128, 128, 128, 8, wpkV1);
    pack_w<<<(8 * 16 * 128 + 255) / 256, 256, 0, stream>>>(vf_w2, 128, 128, 128, 8, wpkV2);

    // counting sort of edges by row
    k_hist<<<N_EDGES / 256, 256, 0, stream>>>(eidx, cnt_i);
    k_scan1<<<NB, 256, 0, stream>>>(cnt_i, offs, bsum);
    k_scan2<<<1, 256, 0, stream>>>(bsum);
    k_addcur<<<NB, 256, 0, stream>>>(offs, bsum, cursor);
    k_scatter<<<N_EDGES / 256, 256, 0, stream>>>(eidx, cursor, perm);

    edge_kernel<<<N_EDGES / 64, 512, 0, stream>>>(
        node_feat, node_pos, eidx, eattr, perm,
        wpk1, msg_b1, wpk2, msg_b2, wpk3, co_b1, wpk4, co_b2,
        agg_msg, agg_vec);

    node_kernel<<<(N_NODES + 63) / 64, 512, 0, stream>>>(
        node_feat, node_pos,
        wpkF1, fi_b1, wpkF2, fi_b2, wpkV1, vf_b1, wpkV2, vf_b2,
        agg_msg, agg_vec, cnt_i, out);
}

// Round 4
// 641.179 us; speedup vs baseline: 3.1714x; 1.0049x over previous
//
#include <hip/hip_runtime.h>
#include <math.h>

#define N_NODES 50000
#define NTOT    50176   // 196*256, padded node count for the scan
#define NB      196
#define N_EDGES 800000
#define H       128

typedef _Float16 f16x8 __attribute__((ext_vector_type(8)));
typedef _Float16 f16x4 __attribute__((ext_vector_type(4)));
typedef float    f32x4 __attribute__((ext_vector_type(4)));

#define KS2 4     // 128/32

// Edge-kernel LDS regions (byte offsets in one char array)
#define GOFF  0        // G = P_r[row]+P_c[col]  [64][128] f16 = 16 KB
#define MOFF  0        // msg (reuses dead G region)
#define HOFF2 16384    // h / h2  [64][128] f16 = 16 KB
#define EAOFF 32768    // eattr tile [64][32] f16 = 4 KB (stride 64 B, no swizzle)
#define HSTR  256
#define LDSB  36864

__device__ __forceinline__ float fast_rcp(float x) {
#if __has_builtin(__builtin_amdgcn_rcpf)
    return __builtin_amdgcn_rcpf(x);
#else
    return 1.0f / x;
#endif
}
__device__ __forceinline__ float fast_exp2(float x) {
#if __has_builtin(__builtin_amdgcn_exp2f)
    return __builtin_amdgcn_exp2f(x);
#else
    return exp2f(x);
#endif
}
__device__ __forceinline__ float silu_f(float x) {
    return x * fast_rcp(1.0f + fast_exp2(-1.44269504089f * x));
}

// ---------------------------------------------------------------------------
// Fused weight prep: f32 [K][NCOL] -> f16 frag-packed [ct][ks][lane][8]
// element (ct,ks,l,j) = W[ks*32+(l>>4)*8+j][ct*16+(l&15)], zero-padded
// ---------------------------------------------------------------------------
__device__ __forceinline__ void pack_one(const float* __restrict__ W, int K,
                                         int KP, int NCOL,
                                         _Float16* __restrict__ out, int idx) {
    const int KS = KP >> 5;
    const int j = idx & 7, l = (idx >> 3) & 63, rem = idx >> 9;
    const int ct = rem / KS, ks = rem % KS;
    const int k = ks * 32 + (l >> 4) * 8 + j;
    const int c = ct * 16 + (l & 15);
    out[idx] = (_Float16)((k < K && c < NCOL) ? W[k * NCOL + c] : 0.0f);
}

__global__ void pack_all(const float* __restrict__ msg_w1, const float* __restrict__ msg_w2,
                         const float* __restrict__ co_w1, const float* __restrict__ co_w2,
                         const float* __restrict__ fi_w1, const float* __restrict__ fi_w2,
                         const float* __restrict__ vf_w1, const float* __restrict__ vf_w2,
                         _Float16* __restrict__ wR, _Float16* __restrict__ wC,
                         _Float16* __restrict__ wEA, _Float16* __restrict__ w2,
                         _Float16* __restrict__ w3, _Float16* __restrict__ w4,
                         _Float16* __restrict__ wF1, _Float16* __restrict__ wF2,
                         _Float16* __restrict__ wV1, _Float16* __restrict__ wV2,
                         float* __restrict__ wip) {
    const int b = blockIdx.x, t = threadIdx.x;
    if      (b < 64)  pack_one(msg_w1,             128, 128, 128, wR,  b * 256 + t);
    else if (b < 128) pack_one(msg_w1 + 128 * 128, 128, 128, 128, wC,  (b - 64) * 256 + t);
    else if (b < 144) pack_one(msg_w1 + 256 * 128, 32,  32,  128, wEA, (b - 128) * 256 + t);
    else if (b < 208) pack_one(msg_w2, 128, 128, 128, w2,  (b - 144) * 256 + t);
    else if (b < 272) pack_one(co_w1,  128, 128, 128, w3,  (b - 208) * 256 + t);
    else if (b < 280) pack_one(co_w2,  128, 128, 4,   w4,  (b - 272) * 256 + t);
    else if (b < 344) pack_one(fi_w1,  128, 128, 128, wF1, (b - 280) * 256 + t);
    else if (b < 408) pack_one(fi_w2,  128, 128, 128, wF2, (b - 344) * 256 + t);
    else if (b < 472) pack_one(vf_w1,  128, 128, 128, wV1, (b - 408) * 256 + t);
    else if (b < 536) pack_one(vf_w2,  128, 128, 128, wV2, (b - 472) * 256 + t);
    else if (t < 128) wip[t] = msg_w1[288 * 128 + t] + msg_w1[289 * 128 + t]
                             + msg_w1[290 * 128 + t] + msg_w1[291 * 128 + t];
}

// ---------------------------------------------------------------------------
// Counting sort: hist -> 2-level exclusive scan -> scatter (perm)
// ---------------------------------------------------------------------------
__global__ void k_hist(const int* __restrict__ eidx, int* __restrict__ cnt) {
    const int e = blockIdx.x * 256 + threadIdx.x;
    atomicAdd(&cnt[eidx[e]], 1);
}

__global__ void k_scan1(const int* __restrict__ cnt, int* __restrict__ offs,
                        int* __restrict__ bsum) {
    __shared__ int sd[256];
    const int t = threadIdx.x;
    const int idx = blockIdx.x * 256 + t;
    const int v = cnt[idx];
    sd[t] = v;
    __syncthreads();
    for (int off = 1; off < 256; off <<= 1) {
        int x = (t >= off) ? sd[t - off] : 0;
        __syncthreads();
        sd[t] += x;
        __syncthreads();
    }
    offs[idx] = sd[t] - v;
    if (t == 255) bsum[blockIdx.x] = sd[255];
}

__global__ void k_scan2(int* __restrict__ bsum) {
    __shared__ int sd[256];
    const int t = threadIdx.x;
    const int v = (t < NB) ? bsum[t] : 0;
    sd[t] = v;
    __syncthreads();
    for (int off = 1; off < 256; off <<= 1) {
        int x = (t >= off) ? sd[t - off] : 0;
        __syncthreads();
        sd[t] += x;
        __syncthreads();
    }
    if (t < NB) bsum[t] = sd[t] - v;
}

__global__ void k_addcur(int* __restrict__ offs, const int* __restrict__ bsum,
                         int* __restrict__ cursor) {
    const int idx = blockIdx.x * 256 + threadIdx.x;
    const int v = offs[idx] + bsum[blockIdx.x];
    offs[idx] = v;
    cursor[idx] = v;
}

__global__ void k_scatter(const int* __restrict__ eidx, int* __restrict__ cursor,
                          int* __restrict__ perm) {
    const int e = blockIdx.x * 256 + threadIdx.x;
    const int p = atomicAdd(&cursor[eidx[e]], 1);
    perm[p] = e;
}

// ---------------------------------------------------------------------------
// swizzled LDS accessors (byte ^= (row&7)<<4 kills 128B-stride conflicts)
// ---------------------------------------------------------------------------
__device__ __forceinline__ f16x8 ld_frag(const char* sp, int off, int row,
                                         int strideB, int kb) {
    const int byte = (off + row * strideB + kb * 2) ^ ((row & 7) << 4);
    return *(const f16x8*)(sp + byte);
}
__device__ __forceinline__ void st_f16(char* sp, int off, int row, int col,
                                       _Float16 v) {
    const int byte = (off + row * HSTR + col * 2) ^ ((row & 7) << 4);
    *(_Float16*)(sp + byte) = v;
}
__device__ __forceinline__ float ld_f16(const char* sp, int off, int row, int col) {
    const int byte = (off + row * HSTR + col * 2) ^ ((row & 7) << 4);
    return (float)*(const _Float16*)(sp + byte);
}

// one wave: 64 rows x 16 cols (col tile = wave id w), A from LDS, B packed
#define MFMA_GEMM(OFF, STRIDEB, KS, WPK)                                      \
    {                                                                         \
        _Pragma("unroll")                                                     \
        for (int ks = 0; ks < (KS); ++ks) {                                   \
            const f16x8 b = *(const f16x8*)&(WPK)[(((w * (KS)) + ks) * 64 + lane) * 8]; \
            _Pragma("unroll")                                                 \
            for (int rt = 0; rt < 4; ++rt) {                                  \
                const f16x8 a = ld_frag(sp, (OFF), rt * 16 + lr, (STRIDEB),   \
                                        ks * 32 + lk * 8);                    \
                acc[rt] = __builtin_amdgcn_mfma_f32_16x16x32_f16(a, b, acc[rt], 0, 0, 0); \
            }                                                                 \
        }                                                                     \
    }

#define ACC_ZERO { _Pragma("unroll") for (int rt = 0; rt < 4; ++rt) acc[rt] = (f32x4)0.0f; }

// epilogue: C row = rt*16 + lk*4 + i, col = w*16 + lr
#define EPILOGUE(OFF, BIAS, ACT)                                              \
    {                                                                         \
        const int col = w * 16 + lr;                                          \
        const float bv = (BIAS)[col];                                         \
        _Pragma("unroll")                                                     \
        for (int rt = 0; rt < 4; ++rt) {                                      \
            _Pragma("unroll")                                                 \
            for (int i = 0; i < 4; ++i) {                                     \
                float v = acc[rt][i] + bv;                                    \
                if (ACT) v = silu_f(v);                                       \
                st_f16(sp, (OFF), rt * 16 + lk * 4 + i, col, (_Float16)v);    \
            }                                                                 \
        }                                                                     \
    }

// ---------------------------------------------------------------------------
// P_r / P_c precompute: pr16[n] = feat[n] @ msg_w1[0:128], pc16 = @[128:256]
// ---------------------------------------------------------------------------
__global__ __launch_bounds__(512, 4) void prc_kernel(
    const float* __restrict__ feat,
    const _Float16* __restrict__ wR, const _Float16* __restrict__ wC,
    _Float16* __restrict__ pr16, _Float16* __restrict__ pc16)
{
    __shared__ alignas(16) char Sb[16384];
    char* sp = (char*)Sb;
    const int t = threadIdx.x;
    const int lane = t & 63, w = t >> 6;
    const int lr = lane & 15, lk = lane >> 4;
    const int n0 = blockIdx.x * 64;

    const float4* feat4 = (const float4*)feat;
    #pragma unroll
    for (int s = 0; s < 4; ++s) {
        const int flat = t + 512 * s;
        const int e = flat >> 5, q = flat & 31;
        const int node = n0 + e;
        float4 v = make_float4(0.f, 0.f, 0.f, 0.f);
        if (node < N_NODES) v = feat4[(size_t)node * 32 + q];
        f16x4 o; o[0]=(_Float16)v.x; o[1]=(_Float16)v.y; o[2]=(_Float16)v.z; o[3]=(_Float16)v.w;
        const int byte = (e * HSTR + q * 8) ^ ((e & 7) << 4);
        *(f16x4*)(sp + byte) = o;
    }
    __syncthreads();

    f32x4 acc[4];
    const int col = w * 16 + lr;

    ACC_ZERO
    MFMA_GEMM(0, HSTR, KS2, wR)
    #pragma unroll
    for (int rt = 0; rt < 4; ++rt)
        #pragma unroll
        for (int i = 0; i < 4; ++i) {
            const int node = n0 + rt * 16 + lk * 4 + i;
            if (node < N_NODES) pr16[(size_t)node * H + col] = (_Float16)acc[rt][i];
        }

    ACC_ZERO
    MFMA_GEMM(0, HSTR, KS2, wC)
    #pragma unroll
    for (int rt = 0; rt < 4; ++rt)
        #pragma unroll
        for (int i = 0; i < 4; ++i) {
            const int node = n0 + rt * 16 + lk * 4 + i;
            if (node < N_NODES) pc16[(size_t)node * H + col] = (_Float16)acc[rt][i];
        }
}

// ---------------------------------------------------------------------------
// Edge kernel: G-gather -> EA-MFMA(+G+dsq*wip) -> msg/coff MFMA -> run agg
// ---------------------------------------------------------------------------
__global__ __launch_bounds__(512, 8) void edge_kernel(
    const _Float16* __restrict__ pr16, const _Float16* __restrict__ pc16,
    const float* __restrict__ pos,
    const int* __restrict__ eidx, const float* __restrict__ eattr,
    const int* __restrict__ perm,
    const _Float16* __restrict__ wEA, const float* __restrict__ wip,
    const float* __restrict__ mb1,
    const _Float16* __restrict__ wpk2, const float* __restrict__ mb2,
    const _Float16* __restrict__ wpk3, const float* __restrict__ cb1,
    const _Float16* __restrict__ wpk4, const float* __restrict__ cb2,
    float* __restrict__ agg_msg, float* __restrict__ agg_vec)
{
    __shared__ alignas(16) char Sb[LDSB];
    __shared__ float unitS[64][3];
    __shared__ float coffS[64][4];
    __shared__ float dsqS[64];
    __shared__ int   rowS[64];
    __shared__ int   colS[64];
    __shared__ int   peS[64];
    __shared__ int   runListS[65];
    __shared__ int   nRunsS;
    char* sp = (char*)Sb;

    const int t    = threadIdx.x;
    const int lane = t & 63;
    const int w    = t >> 6;
    const int lr   = lane & 15;
    const int lk   = lane >> 4;
    const int e0   = blockIdx.x * 64;

    // --- phase 0: geometry + run detection (wave 0) ---
    if (t < 64) {
        const int pe = perm[e0 + t];
        const int r = eidx[pe];
        const int c = eidx[N_EDGES + pe];
        peS[t] = pe; rowS[t] = r; colS[t] = c;
        const float dx = pos[r*3+0] - pos[c*3+0];
        const float dy = pos[r*3+1] - pos[c*3+1];
        const float dz = pos[r*3+2] - pos[c*3+2];
        const float dsq = dx*dx + dy*dy + dz*dz;
        const float inv = 1.0f / fmaxf(sqrtf(dsq), 1e-8f);
        unitS[t][0] = dx * inv;
        unitS[t][1] = dy * inv;
        unitS[t][2] = dz * inv;
        dsqS[t] = dsq;
        const int prev = __shfl_up(r, 1);
        const bool isStart = (t == 0) || (prev != r);
        const unsigned long long mask = __ballot(isStart);
        const int nR = __popcll(mask);
        if (isStart) runListS[__popcll(mask & ((1ull << t) - 1))] = t;
        if (t == 0)  nRunsS = nR;
        if (t == 63) runListS[nR] = 64;
    }
    __syncthreads();

    // --- phase 1: G = P_r[row] + P_c[col] (f16 pk-adds) + eattr tile ---
    #pragma unroll
    for (int s = 0; s < 2; ++s) {
        const int flat = t + 512 * s;          // 0..1023
        const int e = flat >> 4, q = flat & 15;
        const f16x8 a = *(const f16x8*)&pr16[(size_t)rowS[e] * H + q * 8];
        const f16x8 b = *(const f16x8*)&pc16[(size_t)colS[e] * H + q * 8];
        const f16x8 g = a + b;
        const int byte = (GOFF + e * HSTR + q * 16) ^ ((e & 7) << 4);
        *(f16x8*)(sp + byte) = g;
    }
    {   // eattr: [64][32] f16, stride 64 B (2-way bank alias = free)
        const int e = t >> 3, q = t & 7;
        const float4 v = ((const float4*)eattr)[(size_t)peS[e] * 8 + q];
        f16x4 o; o[0]=(_Float16)v.x; o[1]=(_Float16)v.y; o[2]=(_Float16)v.z; o[3]=(_Float16)v.w;
        *(f16x4*)(sp + EAOFF + e * 64 + q * 8) = o;
    }
    __syncthreads();

    f32x4 acc[4];
    const int col = w * 16 + lr;

    // ---- EA GEMM: h = silu(G + ea@W_ea + dsq*wip + mb1) ----
    ACC_ZERO
    {
        const f16x8 bEA = *(const f16x8*)&wEA[(w * 64 + lane) * 8];
        #pragma unroll
        for (int rt = 0; rt < 4; ++rt) {
            const f16x8 a = *(const f16x8*)(sp + EAOFF + (rt * 16 + lr) * 64 + lk * 16);
            acc[rt] = __builtin_amdgcn_mfma_f32_16x16x32_f16(a, bEA, acc[rt], 0, 0, 0);
        }
    }
    {
        const float bv = mb1[col];
        const float wipv = wip[col];
        #pragma unroll
        for (int rt = 0; rt < 4; ++rt)
            #pragma unroll
            for (int i = 0; i < 4; ++i) {
                const int row = rt * 16 + lk * 4 + i;
                float v = acc[rt][i] + bv + dsqS[row] * wipv + ld_f16(sp, GOFF, row, col);
                st_f16(sp, HOFF2, row, col, (_Float16)silu_f(v));
            }
    }
    __syncthreads();

    // ---- GEMM2: msg = h @ mw2 + mb2 (msg overwrites dead G region) ----
    ACC_ZERO
    MFMA_GEMM(HOFF2, HSTR, KS2, wpk2)
    EPILOGUE(MOFF, mb2, 0)
    __syncthreads();

    // ---- GEMM3: h2 = silu(msg @ cw1 + cb1), overwrite h region ----
    ACC_ZERO
    MFMA_GEMM(MOFF, HSTR, KS2, wpk3)
    EPILOGUE(HOFF2, cb1, 1)
    __syncthreads();

    // ---- GEMM4 (waves 0-3): coff = h2 @ cw2 + cb2 ----
    if (w < 4) {
        f32x4 a4 = (f32x4)0.0f;
        #pragma unroll
        for (int ks = 0; ks < 4; ++ks) {
            const f16x8 b = *(const f16x8*)&wpk4[(ks * 64 + lane) * 8];
            const f16x8 a = ld_frag(sp, HOFF2, w * 16 + lr, HSTR, ks * 32 + lk * 8);
            a4 = __builtin_amdgcn_mfma_f32_16x16x32_f16(a, b, a4, 0, 0, 0);
        }
        if (lr < 4) {
            #pragma unroll
            for (int i = 0; i < 4; ++i)
                coffS[w * 16 + lk * 4 + i][lr] = a4[i] + cb2[lr];
        }
    } else {
        // ---- run-compressed msg aggregation (waves 4-7), f16x8 vectorized ----
        const int nR = nRunsS;
        for (int it = t - 256; it < nR * 16; it += 256) {
            const int run = it >> 4, q = it & 15;
            const int s = runListS[run], e1 = runListS[run + 1];
            float a[8] = {0.f, 0.f, 0.f, 0.f, 0.f, 0.f, 0.f, 0.f};
            for (int k = s; k < e1; ++k) {
                const f16x8 v = ld_frag(sp, MOFF, k, HSTR, q * 8);
                #pragma unroll
                for (int j = 0; j < 8; ++j) a[j] += (float)v[j];
            }
            float* dst = &agg_msg[(size_t)rowS[s] * H + q * 8];
            #pragma unroll
            for (int j = 0; j < 8; ++j) atomicAdd(&dst[j], a[j]);
        }
    }
    __syncthreads();

    // ---- run-compressed vec aggregation ----
    const int nR = nRunsS;
    for (int it = t; it < nR * 12; it += 512) {
        const int run = it / 12, m = it % 12;
        const int s = runListS[run], e1 = runListS[run + 1];
        float a = 0.0f;
        for (int k = s; k < e1; ++k) a += coffS[k][m / 3] * unitS[k][m % 3];
        atomicAdd(&agg_vec[(size_t)rowS[s] * 12 + m], a);
    }
}

// ---------------------------------------------------------------------------
// Node kernel (MFMA): vn_feat = siluMLP(feat) + MLP(agg_mean); vn_pos
// ---------------------------------------------------------------------------
#define AOFF 0
#define BOFF 16384
#define NLDS 32768

__global__ __launch_bounds__(512, 4) void node_kernel(
    const float* __restrict__ feat, const float* __restrict__ pos,
    const _Float16* __restrict__ wf1, const float* __restrict__ fb1,
    const _Float16* __restrict__ wf2, const float* __restrict__ fb2,
    const _Float16* __restrict__ wv1, const float* __restrict__ vb1,
    const _Float16* __restrict__ wv2, const float* __restrict__ vb2,
    const float* __restrict__ agg_msg, const float* __restrict__ agg_vec,
    const int* __restrict__ cnt_i, float* __restrict__ out)
{
    __shared__ alignas(16) char Sb[NLDS];
    __shared__ float invS[64];
    char* sp = (char*)Sb;

    const int t    = threadIdx.x;
    const int lane = t & 63;
    const int w    = t >> 6;
    const int lr   = lane & 15;
    const int lk   = lane >> 4;
    const int n0   = blockIdx.x * 64;

    const float4* feat4 = (const float4*)feat;
    #pragma unroll
    for (int s = 0; s < 4; ++s) {
        const int flat = t + 512 * s;
        const int e = flat >> 5, q = flat & 31;
        const int node = n0 + e;
        float4 v = make_float4(0.f, 0.f, 0.f, 0.f);
        if (node < N_NODES) v = feat4[(size_t)node * 32 + q];
        f16x4 o; o[0]=(_Float16)v.x; o[1]=(_Float16)v.y; o[2]=(_Float16)v.z; o[3]=(_Float16)v.w;
        const int byte = (AOFF + e * HSTR + q * 8) ^ ((e & 7) << 4);
        *(f16x4*)(sp + byte) = o;
    }
    if (t < 64) {
        const int node = n0 + t;
        const float c = (node < N_NODES) ? (float)cnt_i[node] : 1.0f;
        invS[t] = fast_rcp(fmaxf(c, 1.0f));
    }
    __syncthreads();

    f32x4 acc[4];
    float resid[4][4];

    ACC_ZERO
    MFMA_GEMM(AOFF, HSTR, KS2, wf1)
    EPILOGUE(BOFF, fb1, 1)
    __syncthreads();

    ACC_ZERO
    MFMA_GEMM(BOFF, HSTR, KS2, wf2)
    {
        const float bv = fb2[w * 16 + lr];
        #pragma unroll
        for (int rt = 0; rt < 4; ++rt)
            #pragma unroll
            for (int i = 0; i < 4; ++i)
                resid[rt][i] = silu_f(acc[rt][i] + bv);
    }
    __syncthreads();

    const float4* agg4 = (const float4*)agg_msg;
    #pragma unroll
    for (int s = 0; s < 4; ++s) {
        const int flat = t + 512 * s;
        const int e = flat >> 5, q = flat & 31;
        const int node = n0 + e;
        float4 v = make_float4(0.f, 0.f, 0.f, 0.f);
        if (node < N_NODES) v = agg4[(size_t)node * 32 + q];
        const float iv = invS[e];
        f16x4 o; o[0]=(_Float16)(v.x*iv); o[1]=(_Float16)(v.y*iv);
        o[2]=(_Float16)(v.z*iv); o[3]=(_Float16)(v.w*iv);
        const int byte = (AOFF + e * HSTR + q * 8) ^ ((e & 7) << 4);
        *(f16x4*)(sp + byte) = o;
    }
    __syncthreads();

    ACC_ZERO
    MFMA_GEMM(AOFF, HSTR, KS2, wv1)
    EPILOGUE(BOFF, vb1, 1)
    __syncthreads();

    ACC_ZERO
    MFMA_GEMM(BOFF, HSTR, KS2, wv2)
    {
        const int col = w * 16 + lr;
        const float bv = vb2[col];
        #pragma unroll
        for (int rt = 0; rt < 4; ++rt) {
            #pragma unroll
            for (int i = 0; i < 4; ++i) {
                const int node = n0 + rt * 16 + lk * 4 + i;
                if (node < N_NODES)
                    out[(size_t)node * H + col] = acc[rt][i] + bv + resid[rt][i];
            }
        }
    }

    for (int fl = t; fl < 64 * 12; fl += 512) {
        const int e = fl / 12, m = fl % 12;
        const int node = n0 + e;
        if (node < N_NODES)
            out[(size_t)N_NODES * H + (size_t)node * 12 + m] =
                pos[node * 3 + (m % 3)] + agg_vec[(size_t)node * 12 + m] * invS[e];
    }
}

extern "C" void kernel_launch(void* const* d_in, const int* in_sizes, int n_in,
                              void* d_out, int out_size, void* d_ws, size_t ws_size,
                              hipStream_t stream)
{
    const float* node_feat = (const float*)d_in[0];
    const float* node_pos  = (const float*)d_in[1];
    const int*   eidx      = (const int*)  d_in[2];
    const float* eattr     = (const float*)d_in[3];
    const float* fi_w1  = (const float*)d_in[4];
    const float* fi_b1  = (const float*)d_in[5];
    const float* fi_w2  = (const float*)d_in[6];
    const float* fi_b2  = (const float*)d_in[7];
    const float* msg_w1 = (const float*)d_in[8];
    const float* msg_b1 = (const float*)d_in[9];
    const float* msg_w2 = (const float*)d_in[10];
    const float* msg_b2 = (const float*)d_in[11];
    const float* co_w1  = (const float*)d_in[12];
    const float* co_b1  = (const float*)d_in[13];
    const float* co_w2  = (const float*)d_in[14];
    const float* co_b2  = (const float*)d_in[15];
    const float* vf_w1  = (const float*)d_in[16];
    const float* vf_b1  = (const float*)d_in[17];
    const float* vf_w2  = (const float*)d_in[18];
    const float* vf_b2  = (const float*)d_in[19];

    float* out     = (float*)d_out;
    float* agg_msg = (float*)d_ws;                          // [N,128] f32
    float* agg_vec = agg_msg + (size_t)N_NODES * H;         // [N,12]  f32
    int*   cnt_i   = (int*)(agg_vec + (size_t)N_NODES * 12);// [NTOT]
    int*   offs    = cnt_i + NTOT;
    int*   cursor  = offs + NTOT;
    int*   bsum    = cursor + NTOT;                         // [256]
    int*   perm    = bsum + 256;                            // [E]
    _Float16* pr16 = (_Float16*)(perm + N_EDGES);           // [N,128]
    _Float16* pc16 = pr16 + (size_t)N_NODES * H;            // [N,128]
    _Float16* wR   = pc16 + (size_t)N_NODES * H;            // 16384
    _Float16* wC   = wR + 16384;
    _Float16* wEA  = wC + 16384;                            // 4096
    _Float16* wpk2 = wEA + 4096;
    _Float16* wpk3 = wpk2 + 16384;
    _Float16* wpk4 = wpk3 + 16384;                          // 2048
    _Float16* wF1  = wpk4 + 2048;
    _Float16* wF2  = wF1 + 16384;
    _Float16* wV1  = wF2 + 16384;
    _Float16* wV2  = wV1 + 16384;
    float*    wip  = (float*)(wV2 + 16384);                 // [128]

    hipMemsetAsync(d_ws, 0,
                   ((size_t)N_NODES * (H + 12) + NTOT) * sizeof(float), stream);

    pack_all<<<537, 256, 0, stream>>>(msg_w1, msg_w2, co_w1, co_w2,
                                      fi_w1, fi_w2, vf_w1, vf_w2,
                                      wR, wC, wEA, wpk2, wpk3, wpk4,
                                      wF1, wF2, wV1, wV2, wip);

    k_hist<<<N_EDGES / 256, 256, 0, stream>>>(eidx, cnt_i);
    k_scan1<<<NB, 256, 0, stream>>>(cnt_i, offs, bsum);
    k_scan2<<<1, 256, 0, stream>>>(bsum);
    k_addcur<<<NB, 256, 0, stream>>>(offs, bsum, cursor);
    k_scatter<<<N_EDGES / 256, 256, 0, stream>>>(eidx, cursor, perm);

    prc_kernel<<<(N_NODES + 63) / 64, 512, 0, stream>>>(node_feat, wR, wC, pr16, pc16);

    edge_kernel<<<N_EDGES / 64, 512, 0, stream>>>(
        pr16, pc16, node_pos, eidx, eattr, perm,
        wEA, wip, msg_b1, wpk2, msg_b2, wpk3, co_b1, wpk4, co_b2,
        agg_msg, agg_vec);

    node_kernel<<<(N_NODES + 63) / 64, 512, 0, stream>>>(
        node_feat, node_pos,
        wF1, fi_b1, wF2, fi_b2, wV1, vf_b1, wV2, vf_b2,
        agg_msg, agg_vec, cnt_i, out);
}

// Round 7
// 637.590 us; speedup vs baseline: 3.1893x; 1.0056x over previous
//
#include <hip/hip_runtime.h>
#include <math.h>

#define N_NODES 50000
#define NTOT    50176   // 196*256, padded node count for the scan
#define NB      196
#define N_EDGES 800000
#define H       128

typedef _Float16 f16x8 __attribute__((ext_vector_type(8)));
typedef _Float16 f16x4 __attribute__((ext_vector_type(4)));
typedef float    f32x4 __attribute__((ext_vector_type(4)));

#define KS2 4     // 128/32

// Edge-kernel LDS regions (byte offsets in one char array)
#define GOFF  0        // G = P_r[row]+P_c[col]  [64][128] f16 = 16 KB
#define MOFF  0        // msg (reuses dead G region)
#define HOFF2 16384    // h / h2  [64][128] f16 = 16 KB
#define EAOFF 32768    // eattr tile [64][32] f16 = 4 KB (stride 64 B, no swizzle)
#define HSTR  256
#define LDSB  36864

__device__ __forceinline__ float fast_rcp(float x) {
#if __has_builtin(__builtin_amdgcn_rcpf)
    return __builtin_amdgcn_rcpf(x);
#else
    return 1.0f / x;
#endif
}
__device__ __forceinline__ float fast_exp2(float x) {
#if __has_builtin(__builtin_amdgcn_exp2f)
    return __builtin_amdgcn_exp2f(x);
#else
    return exp2f(x);
#endif
}
__device__ __forceinline__ float silu_f(float x) {
    return x * fast_rcp(1.0f + fast_exp2(-1.44269504089f * x));
}

// ---------------------------------------------------------------------------
// Fused weight prep: f32 [K][NCOL] -> f16 frag-packed [ct][ks][lane][8]
// element (ct,ks,l,j) = W[ks*32+(l>>4)*8+j][ct*16+(l&15)], zero-padded
// ---------------------------------------------------------------------------
__device__ __forceinline__ void pack_one(const float* __restrict__ W, int K,
                                         int KP, int NCOL,
                                         _Float16* __restrict__ out, int idx) {
    const int KS = KP >> 5;
    const int j = idx & 7, l = (idx >> 3) & 63, rem = idx >> 9;
    const int ct = rem / KS, ks = rem % KS;
    const int k = ks * 32 + (l >> 4) * 8 + j;
    const int c = ct * 16 + (l & 15);
    out[idx] = (_Float16)((k < K && c < NCOL) ? W[k * NCOL + c] : 0.0f);
}

__global__ void pack_all(const float* __restrict__ msg_w1, const float* __restrict__ msg_w2,
                         const float* __restrict__ co_w1, const float* __restrict__ co_w2,
                         const float* __restrict__ fi_w1, const float* __restrict__ fi_w2,
                         const float* __restrict__ vf_w1, const float* __restrict__ vf_w2,
                         _Float16* __restrict__ wR, _Float16* __restrict__ wC,
                         _Float16* __restrict__ wEA, _Float16* __restrict__ w2,
                         _Float16* __restrict__ w3, _Float16* __restrict__ w4,
                         _Float16* __restrict__ wF1, _Float16* __restrict__ wF2,
                         _Float16* __restrict__ wV1, _Float16* __restrict__ wV2,
                         float* __restrict__ wip) {
    const int b = blockIdx.x, t = threadIdx.x;
    if      (b < 64)  pack_one(msg_w1,             128, 128, 128, wR,  b * 256 + t);
    else if (b < 128) pack_one(msg_w1 + 128 * 128, 128, 128, 128, wC,  (b - 64) * 256 + t);
    else if (b < 144) pack_one(msg_w1 + 256 * 128, 32,  32,  128, wEA, (b - 128) * 256 + t);
    else if (b < 208) pack_one(msg_w2, 128, 128, 128, w2,  (b - 144) * 256 + t);
    else if (b < 272) pack_one(co_w1,  128, 128, 128, w3,  (b - 208) * 256 + t);
    else if (b < 280) pack_one(co_w2,  128, 128, 4,   w4,  (b - 272) * 256 + t);
    else if (b < 344) pack_one(fi_w1,  128, 128, 128, wF1, (b - 280) * 256 + t);
    else if (b < 408) pack_one(fi_w2,  128, 128, 128, wF2, (b - 344) * 256 + t);
    else if (b < 472) pack_one(vf_w1,  128, 128, 128, wV1, (b - 408) * 256 + t);
    else if (b < 536) pack_one(vf_w2,  128, 128, 128, wV2, (b - 472) * 256 + t);
    else if (t < 128) wip[t] = msg_w1[288 * 128 + t] + msg_w1[289 * 128 + t]
                             + msg_w1[290 * 128 + t] + msg_w1[291 * 128 + t];
}

// ---------------------------------------------------------------------------
// Counting sort: hist -> 2-level exclusive scan -> scatter (perm)
// ---------------------------------------------------------------------------
__global__ void k_hist(const int* __restrict__ eidx, int* __restrict__ cnt) {
    const int e = blockIdx.x * 256 + threadIdx.x;
    atomicAdd(&cnt[eidx[e]], 1);
}

__global__ void k_scan1(const int* __restrict__ cnt, int* __restrict__ offs,
                        int* __restrict__ bsum) {
    __shared__ int sd[256];
    const int t = threadIdx.x;
    const int idx = blockIdx.x * 256 + t;
    const int v = cnt[idx];
    sd[t] = v;
    __syncthreads();
    for (int off = 1; off < 256; off <<= 1) {
        int x = (t >= off) ? sd[t - off] : 0;
        __syncthreads();
        sd[t] += x;
        __syncthreads();
    }
    offs[idx] = sd[t] - v;
    if (t == 255) bsum[blockIdx.x] = sd[255];
}

__global__ void k_scan2(int* __restrict__ bsum) {
    __shared__ int sd[256];
    const int t = threadIdx.x;
    const int v = (t < NB) ? bsum[t] : 0;
    sd[t] = v;
    __syncthreads();
    for (int off = 1; off < 256; off <<= 1) {
        int x = (t >= off) ? sd[t - off] : 0;
        __syncthreads();
        sd[t] += x;
        __syncthreads();
    }
    if (t < NB) bsum[t] = sd[t] - v;
}

__global__ void k_addcur(int* __restrict__ offs, const int* __restrict__ bsum,
                         int* __restrict__ cursor) {
    const int idx = blockIdx.x * 256 + threadIdx.x;
    const int v = offs[idx] + bsum[blockIdx.x];
    offs[idx] = v;
    cursor[idx] = v;
}

__global__ void k_scatter(const int* __restrict__ eidx, int* __restrict__ cursor,
                          int* __restrict__ perm) {
    const int e = blockIdx.x * 256 + threadIdx.x;
    const int p = atomicAdd(&cursor[eidx[e]], 1);
    perm[p] = e;
}

// ---------------------------------------------------------------------------
// swizzled LDS accessors (byte ^= (row&7)<<4 kills 128B-stride conflicts)
// ---------------------------------------------------------------------------
__device__ __forceinline__ f16x8 ld_frag(const char* sp, int off, int row,
                                         int strideB, int kb) {
    const int byte = (off + row * strideB + kb * 2) ^ ((row & 7) << 4);
    return *(const f16x8*)(sp + byte);
}
__device__ __forceinline__ void st_f16(char* sp, int off, int row, int col,
                                       _Float16 v) {
    const int byte = (off + row * HSTR + col * 2) ^ ((row & 7) << 4);
    *(_Float16*)(sp + byte) = v;
}
__device__ __forceinline__ float ld_f16(const char* sp, int off, int row, int col) {
    const int byte = (off + row * HSTR + col * 2) ^ ((row & 7) << 4);
    return (float)*(const _Float16*)(sp + byte);
}

// one wave: 64 rows x 16 cols (col tile = wave id w), A from LDS, B packed
#define MFMA_GEMM(OFF, STRIDEB, KS, WPK)                                      \
    {                                                                         \
        _Pragma("unroll")                                                     \
        for (int ks = 0; ks < (KS); ++ks) {                                   \
            const f16x8 b = *(const f16x8*)&(WPK)[(((w * (KS)) + ks) * 64 + lane) * 8]; \
            _Pragma("unroll")                                                 \
            for (int rt = 0; rt < 4; ++rt) {                                  \
                const f16x8 a = ld_frag(sp, (OFF), rt * 16 + lr, (STRIDEB),   \
                                        ks * 32 + lk * 8);                    \
                acc[rt] = __builtin_amdgcn_mfma_f32_16x16x32_f16(a, b, acc[rt], 0, 0, 0); \
            }                                                                 \
        }                                                                     \
    }

#define ACC_ZERO { _Pragma("unroll") for (int rt = 0; rt < 4; ++rt) acc[rt] = (f32x4)0.0f; }

// epilogue: C row = rt*16 + lk*4 + i, col = w*16 + lr
#define EPILOGUE(OFF, BIAS, ACT)                                              \
    {                                                                         \
        const int col = w * 16 + lr;                                          \
        const float bv = (BIAS)[col];                                         \
        _Pragma("unroll")                                                     \
        for (int rt = 0; rt < 4; ++rt) {                                      \
            _Pragma("unroll")                                                 \
            for (int i = 0; i < 4; ++i) {                                     \
                float v = acc[rt][i] + bv;                                    \
                if (ACT) v = silu_f(v);                                       \
                st_f16(sp, (OFF), rt * 16 + lk * 4 + i, col, (_Float16)v);    \
            }                                                                 \
        }                                                                     \
    }

// ---------------------------------------------------------------------------
// P_r / P_c precompute: pr16[n] = feat[n] @ msg_w1[0:128], pc16 = @[128:256]
// ---------------------------------------------------------------------------
__global__ __launch_bounds__(512, 4) void prc_kernel(
    const float* __restrict__ feat,
    const _Float16* __restrict__ wR, const _Float16* __restrict__ wC,
    _Float16* __restrict__ pr16, _Float16* __restrict__ pc16)
{
    __shared__ alignas(16) char Sb[16384];
    char* sp = (char*)Sb;
    const int t = threadIdx.x;
    const int lane = t & 63, w = t >> 6;
    const int lr = lane & 15, lk = lane >> 4;
    const int n0 = blockIdx.x * 64;

    const float4* feat4 = (const float4*)feat;
    #pragma unroll
    for (int s = 0; s < 4; ++s) {
        const int flat = t + 512 * s;
        const int e = flat >> 5, q = flat & 31;
        const int node = n0 + e;
        float4 v = make_float4(0.f, 0.f, 0.f, 0.f);
        if (node < N_NODES) v = feat4[(size_t)node * 32 + q];
        f16x4 o; o[0]=(_Float16)v.x; o[1]=(_Float16)v.y; o[2]=(_Float16)v.z; o[3]=(_Float16)v.w;
        const int byte = (e * HSTR + q * 8) ^ ((e & 7) << 4);
        *(f16x4*)(sp + byte) = o;
    }
    __syncthreads();

    f32x4 acc[4];
    const int col = w * 16 + lr;

    ACC_ZERO
    MFMA_GEMM(0, HSTR, KS2, wR)
    #pragma unroll
    for (int rt = 0; rt < 4; ++rt)
        #pragma unroll
        for (int i = 0; i < 4; ++i) {
            const int node = n0 + rt * 16 + lk * 4 + i;
            if (node < N_NODES) pr16[(size_t)node * H + col] = (_Float16)acc[rt][i];
        }

    ACC_ZERO
    MFMA_GEMM(0, HSTR, KS2, wC)
    #pragma unroll
    for (int rt = 0; rt < 4; ++rt)
        #pragma unroll
        for (int i = 0; i < 4; ++i) {
            const int node = n0 + rt * 16 + lk * 4 + i;
            if (node < N_NODES) pc16[(size_t)node * H + col] = (_Float16)acc[rt][i];
        }
}

// ---------------------------------------------------------------------------
// Edge kernel: G-gather -> EA-MFMA(+G+dsq*wip) -> msg/coff MFMA -> run agg
// launch_bounds (512,6): VGPR cap ~84 (this compute fits in 64; (512,8)'s
// cap of 32-64 caused ~20-reg scratch spill -> 516 MB extra HBM writes)
// ---------------------------------------------------------------------------
__global__ __launch_bounds__(512, 6) void edge_kernel(
    const _Float16* __restrict__ pr16, const _Float16* __restrict__ pc16,
    const float* __restrict__ pos,
    const int* __restrict__ eidx, const float* __restrict__ eattr,
    const int* __restrict__ perm,
    const _Float16* __restrict__ wEA, const float* __restrict__ wip,
    const float* __restrict__ mb1,
    const _Float16* __restrict__ wpk2, const float* __restrict__ mb2,
    const _Float16* __restrict__ wpk3, const float* __restrict__ cb1,
    const _Float16* __restrict__ wpk4, const float* __restrict__ cb2,
    float* __restrict__ agg_msg, float* __restrict__ agg_vec)
{
    __shared__ alignas(16) char Sb[LDSB];
    __shared__ float unitS[64][3];
    __shared__ float coffS[64][4];
    __shared__ float dsqS[64];
    __shared__ int   rowS[64];
    __shared__ int   colS[64];
    __shared__ int   peS[64];
    __shared__ int   runListS[65];
    __shared__ int   nRunsS;
    char* sp = (char*)Sb;

    const int t    = threadIdx.x;
    const int lane = t & 63;
    const int w    = t >> 6;
    const int lr   = lane & 15;
    const int lk   = lane >> 4;
    const int e0   = blockIdx.x * 64;

    // --- phase 0: geometry + run detection (wave 0) ---
    if (t < 64) {
        const int pe = perm[e0 + t];
        const int r = eidx[pe];
        const int c = eidx[N_EDGES + pe];
        peS[t] = pe; rowS[t] = r; colS[t] = c;
        const float dx = pos[r*3+0] - pos[c*3+0];
        const float dy = pos[r*3+1] - pos[c*3+1];
        const float dz = pos[r*3+2] - pos[c*3+2];
        const float dsq = dx*dx + dy*dy + dz*dz;
        const float inv = 1.0f / fmaxf(sqrtf(dsq), 1e-8f);
        unitS[t][0] = dx * inv;
        unitS[t][1] = dy * inv;
        unitS[t][2] = dz * inv;
        dsqS[t] = dsq;
        const int prev = __shfl_up(r, 1);
        const bool isStart = (t == 0) || (prev != r);
        const unsigned long long mask = __ballot(isStart);
        const int nR = __popcll(mask);
        if (isStart) runListS[__popcll(mask & ((1ull << t) - 1))] = t;
        if (t == 0)  nRunsS = nR;
        if (t == 63) runListS[nR] = 64;
    }
    __syncthreads();

    // --- phase 1: G = P_r[row] + P_c[col] (f16 pk-adds) + eattr tile ---
    #pragma unroll
    for (int s = 0; s < 2; ++s) {
        const int flat = t + 512 * s;          // 0..1023
        const int e = flat >> 4, q = flat & 15;
        const f16x8 a = *(const f16x8*)&pr16[(size_t)rowS[e] * H + q * 8];
        const f16x8 b = *(const f16x8*)&pc16[(size_t)colS[e] * H + q * 8];
        const f16x8 g = a + b;
        const int byte = (GOFF + e * HSTR + q * 16) ^ ((e & 7) << 4);
        *(f16x8*)(sp + byte) = g;
    }
    {   // eattr: [64][32] f16, stride 64 B (2-way bank alias = free)
        const int e = t >> 3, q = t & 7;
        const float4 v = ((const float4*)eattr)[(size_t)peS[e] * 8 + q];
        f16x4 o; o[0]=(_Float16)v.x; o[1]=(_Float16)v.y; o[2]=(_Float16)v.z; o[3]=(_Float16)v.w;
        *(f16x4*)(sp + EAOFF + e * 64 + q * 8) = o;
    }
    __syncthreads();

    f32x4 acc[4];
    const int col = w * 16 + lr;

    // ---- EA GEMM: h = silu(G + ea@W_ea + dsq*wip + mb1) ----
    ACC_ZERO
    {
        const f16x8 bEA = *(const f16x8*)&wEA[(w * 64 + lane) * 8];
        #pragma unroll
        for (int rt = 0; rt < 4; ++rt) {
            const f16x8 a = *(const f16x8*)(sp + EAOFF + (rt * 16 + lr) * 64 + lk * 16);
            acc[rt] = __builtin_amdgcn_mfma_f32_16x16x32_f16(a, bEA, acc[rt], 0, 0, 0);
        }
    }
    {
        const float bv = mb1[col];
        const float wipv = wip[col];
        #pragma unroll
        for (int rt = 0; rt < 4; ++rt)
            #pragma unroll
            for (int i = 0; i < 4; ++i) {
                const int row = rt * 16 + lk * 4 + i;
                float v = acc[rt][i] + bv + dsqS[row] * wipv + ld_f16(sp, GOFF, row, col);
                st_f16(sp, HOFF2, row, col, (_Float16)silu_f(v));
            }
    }
    __syncthreads();

    // ---- GEMM2: msg = h @ mw2 + mb2 (msg overwrites dead G region) ----
    ACC_ZERO
    MFMA_GEMM(HOFF2, HSTR, KS2, wpk2)
    EPILOGUE(MOFF, mb2, 0)
    __syncthreads();

    // ---- GEMM3: h2 = silu(msg @ cw1 + cb1), overwrite h region ----
    ACC_ZERO
    MFMA_GEMM(MOFF, HSTR, KS2, wpk3)
    EPILOGUE(HOFF2, cb1, 1)
    __syncthreads();

    // ---- GEMM4 (waves 0-3): coff = h2 @ cw2 + cb2 ----
    if (w < 4) {
        f32x4 a4 = (f32x4)0.0f;
        #pragma unroll
        for (int ks = 0; ks < 4; ++ks) {
            const f16x8 b = *(const f16x8*)&wpk4[(ks * 64 + lane) * 8];
            const f16x8 a = ld_frag(sp, HOFF2, w * 16 + lr, HSTR, ks * 32 + lk * 8);
            a4 = __builtin_amdgcn_mfma_f32_16x16x32_f16(a, b, a4, 0, 0, 0);
        }
        if (lr < 4) {
            #pragma unroll
            for (int i = 0; i < 4; ++i)
                coffS[w * 16 + lk * 4 + i][lr] = a4[i] + cb2[lr];
        }
    } else {
        // ---- run-compressed msg aggregation (waves 4-7), f16x8 vectorized ----
        const int nR = nRunsS;
        for (int it = t - 256; it < nR * 16; it += 256) {
            const int run = it >> 4, q = it & 15;
            const int s = runListS[run], e1 = runListS[run + 1];
            float a[8] = {0.f, 0.f, 0.f, 0.f, 0.f, 0.f, 0.f, 0.f};
            for (int k = s; k < e1; ++k) {
                const f16x8 v = ld_frag(sp, MOFF, k, HSTR, q * 8);
                #pragma unroll
                for (int j = 0; j < 8; ++j) a[j] += (float)v[j];
            }
            float* dst = &agg_msg[(size_t)rowS[s] * H + q * 8];
            #pragma unroll
            for (int j = 0; j < 8; ++j) atomicAdd(&dst[j], a[j]);
        }
    }
    __syncthreads();

    // ---- run-compressed vec aggregation ----
    const int nR = nRunsS;
    for (int it = t; it < nR * 12; it += 512) {
        const int run = it / 12, m = it % 12;
        const int s = runListS[run], e1 = runListS[run + 1];
        float a = 0.0f;
        for (int k = s; k < e1; ++k) a += coffS[k][m / 3] * unitS[k][m % 3];
        atomicAdd(&agg_vec[(size_t)rowS[s] * 12 + m], a);
    }
}

// ---------------------------------------------------------------------------
// Node kernel (MFMA): vn_feat = siluMLP(feat) + MLP(agg_mean); vn_pos
// ---------------------------------------------------------------------------
#define AOFF 0
#define BOFF 16384
#define NLDS 32768

__global__ __launch_bounds__(512, 4) void node_kernel(
    const float* __restrict__ feat, const float* __restrict__ pos,
    const _Float16* __restrict__ wf1, const float* __restrict__ fb1,
    const _Float16* __restrict__ wf2, const float* __restrict__ fb2,
    const _Float16* __restrict__ wv1, const float* __restrict__ vb1,
    const _Float16* __restrict__ wv2, const float* __restrict__ vb2,
    const float* __restrict__ agg_msg, const float* __restrict__ agg_vec,
    const int* __restrict__ cnt_i, float* __restrict__ out)
{
    __shared__ alignas(16) char Sb[NLDS];
    __shared__ float invS[64];
    char* sp = (char*)Sb;

    const int t    = threadIdx.x;
    const int lane = t & 63;
    const int w    = t >> 6;
    const int lr   = lane & 15;
    const int lk   = lane >> 4;
    const int n0   = blockIdx.x * 64;

    const float4* feat4 = (const float4*)feat;
    #pragma unroll
    for (int s = 0; s < 4; ++s) {
        const int flat = t + 512 * s;
        const int e = flat >> 5, q = flat & 31;
        const int node = n0 + e;
        float4 v = make_float4(0.f, 0.f, 0.f, 0.f);
        if (node < N_NODES) v = feat4[(size_t)node * 32 + q];
        f16x4 o; o[0]=(_Float16)v.x; o[1]=(_Float16)v.y; o[2]=(_Float16)v.z; o[3]=(_Float16)v.w;
        const int byte = (AOFF + e * HSTR + q * 8) ^ ((e & 7) << 4);
        *(f16x4*)(sp + byte) = o;
    }
    if (t < 64) {
        const int node = n0 + t;
        const float c = (node < N_NODES) ? (float)cnt_i[node] : 1.0f;
        invS[t] = fast_rcp(fmaxf(c, 1.0f));
    }
    __syncthreads();

    f32x4 acc[4];
    float resid[4][4];

    ACC_ZERO
    MFMA_GEMM(AOFF, HSTR, KS2, wf1)
    EPILOGUE(BOFF, fb1, 1)
    __syncthreads();

    ACC_ZERO
    MFMA_GEMM(BOFF, HSTR, KS2, wf2)
    {
        const float bv = fb2[w * 16 + lr];
        #pragma unroll
        for (int rt = 0; rt < 4; ++rt)
            #pragma unroll
            for (int i = 0; i < 4; ++i)
                resid[rt][i] = silu_f(acc[rt][i] + bv);
    }
    __syncthreads();

    const float4* agg4 = (const float4*)agg_msg;
    #pragma unroll
    for (int s = 0; s < 4; ++s) {
        const int flat = t + 512 * s;
        const int e = flat >> 5, q = flat & 31;
        const int node = n0 + e;
        float4 v = make_float4(0.f, 0.f, 0.f, 0.f);
        if (node < N_NODES) v = agg4[(size_t)node * 32 + q];
        const float iv = invS[e];
        f16x4 o; o[0]=(_Float16)(v.x*iv); o[1]=(_Float16)(v.y*iv);
        o[2]=(_Float16)(v.z*iv); o[3]=(_Float16)(v.w*iv);
        const int byte = (AOFF + e * HSTR + q * 8) ^ ((e & 7) << 4);
        *(f16x4*)(sp + byte) = o;
    }
    __syncthreads();

    ACC_ZERO
    MFMA_GEMM(AOFF, HSTR, KS2, wv1)
    EPILOGUE(BOFF, vb1, 1)
    __syncthreads();

    ACC_ZERO
    MFMA_GEMM(BOFF, HSTR, KS2, wv2)
    {
        const int col = w * 16 + lr;
        const float bv = vb2[col];
        #pragma unroll
        for (int rt = 0; rt < 4; ++rt) {
            #pragma unroll
            for (int i = 0; i < 4; ++i) {
                const int node = n0 + rt * 16 + lk * 4 + i;
                if (node < N_NODES)
                    out[(size_t)node * H + col] = acc[rt][i] + bv + resid[rt][i];
            }
        }
    }

    for (int fl = t; fl < 64 * 12; fl += 512) {
        const int e = fl / 12, m = fl % 12;
        const int node = n0 + e;
        if (node < N_NODES)
            out[(size_t)N_NODES * H + (size_t)node * 12 + m] =
                pos[node * 3 + (m % 3)] + agg_vec[(size_t)node * 12 + m] * invS[e];
    }
}

extern "C" void kernel_launch(void* const* d_in, const int* in_sizes, int n_in,
                              void* d_out, int out_size, void* d_ws, size_t ws_size,
                              hipStream_t stream)
{
    const float* node_feat = (const float*)d_in[0];
    const float* node_pos  = (const float*)d_in[1];
    const int*   eidx      = (const int*)  d_in[2];
    const float* eattr     = (const float*)d_in[3];
    const float* fi_w1  = (const float*)d_in[4];
    const float* fi_b1  = (const float*)d_in[5];
    const float* fi_w2  = (const float*)d_in[6];
    const float* fi_b2  = (const float*)d_in[7];
    const float* msg_w1 = (const float*)d_in[8];
    const float* msg_b1 = (const float*)d_in[9];
    const float* msg_w2 = (const float*)d_in[10];
    const float* msg_b2 = (const float*)d_in[11];
    const float* co_w1  = (const float*)d_in[12];
    const float* co_b1  = (const float*)d_in[13];
    const float* co_w2  = (const float*)d_in[14];
    const float* co_b2  = (const float*)d_in[15];
    const float* vf_w1  = (const float*)d_in[16];
    const float* vf_b1  = (const float*)d_in[17];
    const float* vf_w2  = (const float*)d_in[18];
    const float* vf_b2  = (const float*)d_in[19];

    float* out     = (float*)d_out;
    float* agg_msg = (float*)d_ws;                          // [N,128] f32
    float* agg_vec = agg_msg + (size_t)N_NODES * H;         // [N,12]  f32
    int*   cnt_i   = (int*)(agg_vec + (size_t)N_NODES * 12);// [NTOT]
    int*   offs    = cnt_i + NTOT;
    int*   cursor  = offs + NTOT;
    int*   bsum    = cursor + NTOT;                         // [256]
    int*   perm    = bsum + 256;                            // [E]
    _Float16* pr16 = (_Float16*)(perm + N_EDGES);           // [N,128]
    _Float16* pc16 = pr16 + (size_t)N_NODES * H;            // [N,128]
    _Float16* wR   = pc16 + (size_t)N_NODES * H;            // 16384
    _Float16* wC   = wR + 16384;
    _Float16* wEA  = wC + 16384;                            // 4096
    _Float16* wpk2 = wEA + 4096;
    _Float16* wpk3 = wpk2 + 16384;
    _Float16* wpk4 = wpk3 + 16384;                          // 2048
    _Float16* wF1  = wpk4 + 2048;
    _Float16* wF2  = wF1 + 16384;
    _Float16* wV1  = wF2 + 16384;
    _Float16* wV2  = wV1 + 16384;
    float*    wip  = (float*)(wV2 + 16384);                 // [128]

    hipMemsetAsync(d_ws, 0,
                   ((size_t)N_NODES * (H + 12) + NTOT) * sizeof(float), stream);

    pack_all<<<537, 256, 0, stream>>>(msg_w1, msg_w2, co_w1, co_w2,
                                      fi_w1, fi_w2, vf_w1, vf_w2,
                                      wR, wC, wEA, wpk2, wpk3, wpk4,
                                      wF1, wF2, wV1, wV2, wip);

    k_hist<<<N_EDGES / 256, 256, 0, stream>>>(eidx, cnt_i);
    k_scan1<<<NB, 256, 0, stream>>>(cnt_i, offs, bsum);
    k_scan2<<<1, 256, 0, stream>>>(bsum);
    k_addcur<<<NB, 256, 0, stream>>>(offs, bsum, cursor);
    k_scatter<<<N_EDGES / 256, 256, 0, stream>>>(eidx, cursor, perm);

    prc_kernel<<<(N_NODES + 63) / 64, 512, 0, stream>>>(node_feat, wR, wC, pr16, pc16);

    edge_kernel<<<N_EDGES / 64, 512, 0, stream>>>(
        pr16, pc16, node_pos, eidx, eattr, perm,
        wEA, wip, msg_b1, wpk2, msg_b2, wpk3, co_b1, wpk4, co_b2,
        agg_msg, agg_vec);

    node_kernel<<<(N_NODES + 63) / 64, 512, 0, stream>>>(
        node_feat, node_pos,
        wF1, fi_b1, wF2, fi_b2, wV1, vf_b1, wV2, vf_b2,
        agg_msg, agg_vec, cnt_i, out);
}

// Round 8
// 615.215 us; speedup vs baseline: 3.3053x; 1.0364x over previous
//
#include <hip/hip_runtime.h>
#include <math.h>

#define N_NODES 50000
#define NTOT    50176   // 196*256, padded node count for the scan
#define NB      196
#define N_EDGES 800000
#define H       128

typedef _Float16 f16x8 __attribute__((ext_vector_type(8)));
typedef _Float16 f16x4 __attribute__((ext_vector_type(4)));
typedef float    f32x4 __attribute__((ext_vector_type(4)));

#define KS2 4     // 128/32

// Edge-kernel LDS regions (byte offsets in one char array)
#define GOFF  0        // G = P_r[row]+P_c[col]  [64][128] f16 = 16 KB
#define MOFF  0        // msg (reuses dead G region)
#define HOFF2 16384    // h / h2  [64][128] f16 = 16 KB
#define EAOFF 32768    // eattr tile [64][32] f16 = 4 KB (stride 64 B, no swizzle)
#define HSTR  256
#define LDSB  36864

__device__ __forceinline__ float fast_rcp(float x) {
#if __has_builtin(__builtin_amdgcn_rcpf)
    return __builtin_amdgcn_rcpf(x);
#else
    return 1.0f / x;
#endif
}
__device__ __forceinline__ float fast_exp2(float x) {
#if __has_builtin(__builtin_amdgcn_exp2f)
    return __builtin_amdgcn_exp2f(x);
#else
    return exp2f(x);
#endif
}
__device__ __forceinline__ float silu_f(float x) {
    return x * fast_rcp(1.0f + fast_exp2(-1.44269504089f * x));
}

// ---------------------------------------------------------------------------
// Fused weight prep: f32 [K][NCOL] -> f16 frag-packed [ct][ks][lane][8]
// element (ct,ks,l,j) = W[ks*32+(l>>4)*8+j][ct*16+(l&15)], zero-padded
// ---------------------------------------------------------------------------
__device__ __forceinline__ void pack_one(const float* __restrict__ W, int K,
                                         int KP, int NCOL,
                                         _Float16* __restrict__ out, int idx) {
    const int KS = KP >> 5;
    const int j = idx & 7, l = (idx >> 3) & 63, rem = idx >> 9;
    const int ct = rem / KS, ks = rem % KS;
    const int k = ks * 32 + (l >> 4) * 8 + j;
    const int c = ct * 16 + (l & 15);
    out[idx] = (_Float16)((k < K && c < NCOL) ? W[k * NCOL + c] : 0.0f);
}

__global__ void pack_all(const float* __restrict__ msg_w1, const float* __restrict__ msg_w2,
                         const float* __restrict__ co_w1, const float* __restrict__ co_w2,
                         const float* __restrict__ fi_w1, const float* __restrict__ fi_w2,
                         const float* __restrict__ vf_w1, const float* __restrict__ vf_w2,
                         _Float16* __restrict__ wR, _Float16* __restrict__ wC,
                         _Float16* __restrict__ wEA, _Float16* __restrict__ w2,
                         _Float16* __restrict__ w3, _Float16* __restrict__ w4,
                         _Float16* __restrict__ wF1, _Float16* __restrict__ wF2,
                         _Float16* __restrict__ wV1, _Float16* __restrict__ wV2,
                         float* __restrict__ wip) {
    const int b = blockIdx.x, t = threadIdx.x;
    if      (b < 64)  pack_one(msg_w1,             128, 128, 128, wR,  b * 256 + t);
    else if (b < 128) pack_one(msg_w1 + 128 * 128, 128, 128, 128, wC,  (b - 64) * 256 + t);
    else if (b < 144) pack_one(msg_w1 + 256 * 128, 32,  32,  128, wEA, (b - 128) * 256 + t);
    else if (b < 208) pack_one(msg_w2, 128, 128, 128, w2,  (b - 144) * 256 + t);
    else if (b < 272) pack_one(co_w1,  128, 128, 128, w3,  (b - 208) * 256 + t);
    else if (b < 280) pack_one(co_w2,  128, 128, 4,   w4,  (b - 272) * 256 + t);
    else if (b < 344) pack_one(fi_w1,  128, 128, 128, wF1, (b - 280) * 256 + t);
    else if (b < 408) pack_one(fi_w2,  128, 128, 128, wF2, (b - 344) * 256 + t);
    else if (b < 472) pack_one(vf_w1,  128, 128, 128, wV1, (b - 408) * 256 + t);
    else if (b < 536) pack_one(vf_w2,  128, 128, 128, wV2, (b - 472) * 256 + t);
    else if (t < 128) wip[t] = msg_w1[288 * 128 + t] + msg_w1[289 * 128 + t]
                             + msg_w1[290 * 128 + t] + msg_w1[291 * 128 + t];
}

// ---------------------------------------------------------------------------
// Counting sort: hist -> 2-level exclusive scan -> scatter (perm)
// ---------------------------------------------------------------------------
__global__ void k_hist(const int* __restrict__ eidx, int* __restrict__ cnt) {
    const int e = blockIdx.x * 256 + threadIdx.x;
    atomicAdd(&cnt[eidx[e]], 1);
}

__global__ void k_scan1(const int* __restrict__ cnt, int* __restrict__ offs,
                        int* __restrict__ bsum) {
    __shared__ int sd[256];
    const int t = threadIdx.x;
    const int idx = blockIdx.x * 256 + t;
    const int v = cnt[idx];
    sd[t] = v;
    __syncthreads();
    for (int off = 1; off < 256; off <<= 1) {
        int x = (t >= off) ? sd[t - off] : 0;
        __syncthreads();
        sd[t] += x;
        __syncthreads();
    }
    offs[idx] = sd[t] - v;
    if (t == 255) bsum[blockIdx.x] = sd[255];
}

__global__ void k_scan2(int* __restrict__ bsum) {
    __shared__ int sd[256];
    const int t = threadIdx.x;
    const int v = (t < NB) ? bsum[t] : 0;
    sd[t] = v;
    __syncthreads();
    for (int off = 1; off < 256; off <<= 1) {
        int x = (t >= off) ? sd[t - off] : 0;
        __syncthreads();
        sd[t] += x;
        __syncthreads();
    }
    if (t < NB) bsum[t] = sd[t] - v;
}

__global__ void k_addcur(int* __restrict__ offs, const int* __restrict__ bsum,
                         int* __restrict__ cursor) {
    const int idx = blockIdx.x * 256 + threadIdx.x;
    const int v = offs[idx] + bsum[blockIdx.x];
    offs[idx] = v;
    cursor[idx] = v;
}

__global__ void k_scatter(const int* __restrict__ eidx, int* __restrict__ cursor,
                          int* __restrict__ perm) {
    const int e = blockIdx.x * 256 + threadIdx.x;
    const int p = atomicAdd(&cursor[eidx[e]], 1);
    perm[p] = e;
}

// ---------------------------------------------------------------------------
// swizzled LDS accessors (byte ^= (row&7)<<4 kills 128B-stride conflicts)
// ---------------------------------------------------------------------------
__device__ __forceinline__ f16x8 ld_frag(const char* sp, int off, int row,
                                         int strideB, int kb) {
    const int byte = (off + row * strideB + kb * 2) ^ ((row & 7) << 4);
    return *(const f16x8*)(sp + byte);
}
__device__ __forceinline__ void st_f16(char* sp, int off, int row, int col,
                                       _Float16 v) {
    const int byte = (off + row * HSTR + col * 2) ^ ((row & 7) << 4);
    *(_Float16*)(sp + byte) = v;
}
__device__ __forceinline__ float ld_f16(const char* sp, int off, int row, int col) {
    const int byte = (off + row * HSTR + col * 2) ^ ((row & 7) << 4);
    return (float)*(const _Float16*)(sp + byte);
}

// one wave: 64 rows x 16 cols (col tile = wave id w), A from LDS, B packed
#define MFMA_GEMM(OFF, STRIDEB, KS, WPK)                                      \
    {                                                                         \
        _Pragma("unroll")                                                     \
        for (int ks = 0; ks < (KS); ++ks) {                                   \
            const f16x8 b = *(const f16x8*)&(WPK)[(((w * (KS)) + ks) * 64 + lane) * 8]; \
            _Pragma("unroll")                                                 \
            for (int rt = 0; rt < 4; ++rt) {                                  \
                const f16x8 a = ld_frag(sp, (OFF), rt * 16 + lr, (STRIDEB),   \
                                        ks * 32 + lk * 8);                    \
                acc[rt] = __builtin_amdgcn_mfma_f32_16x16x32_f16(a, b, acc[rt], 0, 0, 0); \
            }                                                                 \
        }                                                                     \
    }

#define ACC_ZERO { _Pragma("unroll") for (int rt = 0; rt < 4; ++rt) acc[rt] = (f32x4)0.0f; }

// epilogue: C row = rt*16 + lk*4 + i, col = w*16 + lr
#define EPILOGUE(OFF, BIAS, ACT)                                              \
    {                                                                         \
        const int col = w * 16 + lr;                                          \
        const float bv = (BIAS)[col];                                         \
        _Pragma("unroll")                                                     \
        for (int rt = 0; rt < 4; ++rt) {                                      \
            _Pragma("unroll")                                                 \
            for (int i = 0; i < 4; ++i) {                                     \
                float v = acc[rt][i] + bv;                                    \
                if (ACT) v = silu_f(v);                                       \
                st_f16(sp, (OFF), rt * 16 + lk * 4 + i, col, (_Float16)v);    \
            }                                                                 \
        }                                                                     \
    }

// ---------------------------------------------------------------------------
// P_r / P_c precompute: pr16[n] = feat[n] @ msg_w1[0:128], pc16 = @[128:256]
// ---------------------------------------------------------------------------
__global__ __launch_bounds__(512, 4) void prc_kernel(
    const float* __restrict__ feat,
    const _Float16* __restrict__ wR, const _Float16* __restrict__ wC,
    _Float16* __restrict__ pr16, _Float16* __restrict__ pc16)
{
    __shared__ alignas(16) char Sb[16384];
    char* sp = (char*)Sb;
    const int t = threadIdx.x;
    const int lane = t & 63, w = t >> 6;
    const int lr = lane & 15, lk = lane >> 4;
    const int n0 = blockIdx.x * 64;

    const float4* feat4 = (const float4*)feat;
    #pragma unroll
    for (int s = 0; s < 4; ++s) {
        const int flat = t + 512 * s;
        const int e = flat >> 5, q = flat & 31;
        const int node = n0 + e;
        float4 v = make_float4(0.f, 0.f, 0.f, 0.f);
        if (node < N_NODES) v = feat4[(size_t)node * 32 + q];
        f16x4 o; o[0]=(_Float16)v.x; o[1]=(_Float16)v.y; o[2]=(_Float16)v.z; o[3]=(_Float16)v.w;
        const int byte = (e * HSTR + q * 8) ^ ((e & 7) << 4);
        *(f16x4*)(sp + byte) = o;
    }
    __syncthreads();

    f32x4 acc[4];
    const int col = w * 16 + lr;

    ACC_ZERO
    MFMA_GEMM(0, HSTR, KS2, wR)
    #pragma unroll
    for (int rt = 0; rt < 4; ++rt)
        #pragma unroll
        for (int i = 0; i < 4; ++i) {
            const int node = n0 + rt * 16 + lk * 4 + i;
            if (node < N_NODES) pr16[(size_t)node * H + col] = (_Float16)acc[rt][i];
        }

    ACC_ZERO
    MFMA_GEMM(0, HSTR, KS2, wC)
    #pragma unroll
    for (int rt = 0; rt < 4; ++rt)
        #pragma unroll
        for (int i = 0; i < 4; ++i) {
            const int node = n0 + rt * 16 + lk * 4 + i;
            if (node < N_NODES) pc16[(size_t)node * H + col] = (_Float16)acc[rt][i];
        }
}

// ---------------------------------------------------------------------------
// Edge kernel: G-gather -> EA-MFMA(+G+dsq*wip) -> msg/coff MFMA -> run agg
// launch_bounds (512,4): reg cap 128/wave. gfx950 has a UNIFIED VGPR/AGPR
// file, so the cap covers both: (512,8)=cap 64 spilled ~20 regs (550 MB
// scratch HBM), (512,6)=cap 84 still spilled ~8 (250 MB). Cap 128 = clean.
// ---------------------------------------------------------------------------
__global__ __launch_bounds__(512, 4) void edge_kernel(
    const _Float16* __restrict__ pr16, const _Float16* __restrict__ pc16,
    const float* __restrict__ pos,
    const int* __restrict__ eidx, const float* __restrict__ eattr,
    const int* __restrict__ perm,
    const _Float16* __restrict__ wEA, const float* __restrict__ wip,
    const float* __restrict__ mb1,
    const _Float16* __restrict__ wpk2, const float* __restrict__ mb2,
    const _Float16* __restrict__ wpk3, const float* __restrict__ cb1,
    const _Float16* __restrict__ wpk4, const float* __restrict__ cb2,
    float* __restrict__ agg_msg, float* __restrict__ agg_vec)
{
    __shared__ alignas(16) char Sb[LDSB];
    __shared__ float unitS[64][3];
    __shared__ float coffS[64][4];
    __shared__ float dsqS[64];
    __shared__ int   rowS[64];
    __shared__ int   colS[64];
    __shared__ int   peS[64];
    __shared__ int   runListS[65];
    __shared__ int   nRunsS;
    char* sp = (char*)Sb;

    const int t    = threadIdx.x;
    const int lane = t & 63;
    const int w    = t >> 6;
    const int lr   = lane & 15;
    const int lk   = lane >> 4;
    const int e0   = blockIdx.x * 64;

    // --- phase 0: geometry + run detection (wave 0) ---
    if (t < 64) {
        const int pe = perm[e0 + t];
        const int r = eidx[pe];
        const int c = eidx[N_EDGES + pe];
        peS[t] = pe; rowS[t] = r; colS[t] = c;
        const float dx = pos[r*3+0] - pos[c*3+0];
        const float dy = pos[r*3+1] - pos[c*3+1];
        const float dz = pos[r*3+2] - pos[c*3+2];
        const float dsq = dx*dx + dy*dy + dz*dz;
        const float inv = 1.0f / fmaxf(sqrtf(dsq), 1e-8f);
        unitS[t][0] = dx * inv;
        unitS[t][1] = dy * inv;
        unitS[t][2] = dz * inv;
        dsqS[t] = dsq;
        const int prev = __shfl_up(r, 1);
        const bool isStart = (t == 0) || (prev != r);
        const unsigned long long mask = __ballot(isStart);
        const int nR = __popcll(mask);
        if (isStart) runListS[__popcll(mask & ((1ull << t) - 1))] = t;
        if (t == 0)  nRunsS = nR;
        if (t == 63) runListS[nR] = 64;
    }
    __syncthreads();

    // --- phase 1: G = P_r[row] + P_c[col] (f16 pk-adds) + eattr tile ---
    #pragma unroll
    for (int s = 0; s < 2; ++s) {
        const int flat = t + 512 * s;          // 0..1023
        const int e = flat >> 4, q = flat & 15;
        const f16x8 a = *(const f16x8*)&pr16[(size_t)rowS[e] * H + q * 8];
        const f16x8 b = *(const f16x8*)&pc16[(size_t)colS[e] * H + q * 8];
        const f16x8 g = a + b;
        const int byte = (GOFF + e * HSTR + q * 16) ^ ((e & 7) << 4);
        *(f16x8*)(sp + byte) = g;
    }
    {   // eattr: [64][32] f16, stride 64 B (2-way bank alias = free)
        const int e = t >> 3, q = t & 7;
        const float4 v = ((const float4*)eattr)[(size_t)peS[e] * 8 + q];
        f16x4 o; o[0]=(_Float16)v.x; o[1]=(_Float16)v.y; o[2]=(_Float16)v.z; o[3]=(_Float16)v.w;
        *(f16x4*)(sp + EAOFF + e * 64 + q * 8) = o;
    }
    __syncthreads();

    f32x4 acc[4];
    const int col = w * 16 + lr;

    // ---- EA GEMM: h = silu(G + ea@W_ea + dsq*wip + mb1) ----
    ACC_ZERO
    {
        const f16x8 bEA = *(const f16x8*)&wEA[(w * 64 + lane) * 8];
        #pragma unroll
        for (int rt = 0; rt < 4; ++rt) {
            const f16x8 a = *(const f16x8*)(sp + EAOFF + (rt * 16 + lr) * 64 + lk * 16);
            acc[rt] = __builtin_amdgcn_mfma_f32_16x16x32_f16(a, bEA, acc[rt], 0, 0, 0);
        }
    }
    {
        const float bv = mb1[col];
        const float wipv = wip[col];
        #pragma unroll
        for (int rt = 0; rt < 4; ++rt)
            #pragma unroll
            for (int i = 0; i < 4; ++i) {
                const int row = rt * 16 + lk * 4 + i;
                float v = acc[rt][i] + bv + dsqS[row] * wipv + ld_f16(sp, GOFF, row, col);
                st_f16(sp, HOFF2, row, col, (_Float16)silu_f(v));
            }
    }
    __syncthreads();

    // ---- GEMM2: msg = h @ mw2 + mb2 (msg overwrites dead G region) ----
    ACC_ZERO
    MFMA_GEMM(HOFF2, HSTR, KS2, wpk2)
    EPILOGUE(MOFF, mb2, 0)
    __syncthreads();

    // ---- GEMM3: h2 = silu(msg @ cw1 + cb1), overwrite h region ----
    ACC_ZERO
    MFMA_GEMM(MOFF, HSTR, KS2, wpk3)
    EPILOGUE(HOFF2, cb1, 1)
    __syncthreads();

    // ---- GEMM4 (waves 0-3): coff = h2 @ cw2 + cb2 ----
    if (w < 4) {
        f32x4 a4 = (f32x4)0.0f;
        #pragma unroll
        for (int ks = 0; ks < 4; ++ks) {
            const f16x8 b = *(const f16x8*)&wpk4[(ks * 64 + lane) * 8];
            const f16x8 a = ld_frag(sp, HOFF2, w * 16 + lr, HSTR, ks * 32 + lk * 8);
            a4 = __builtin_amdgcn_mfma_f32_16x16x32_f16(a, b, a4, 0, 0, 0);
        }
        if (lr < 4) {
            #pragma unroll
            for (int i = 0; i < 4; ++i)
                coffS[w * 16 + lk * 4 + i][lr] = a4[i] + cb2[lr];
        }
    } else {
        // ---- run-compressed msg aggregation (waves 4-7), f16x8 vectorized ----
        const int nR = nRunsS;
        for (int it = t - 256; it < nR * 16; it += 256) {
            const int run = it >> 4, q = it & 15;
            const int s = runListS[run], e1 = runListS[run + 1];
            float a[8] = {0.f, 0.f, 0.f, 0.f, 0.f, 0.f, 0.f, 0.f};
            for (int k = s; k < e1; ++k) {
                const f16x8 v = ld_frag(sp, MOFF, k, HSTR, q * 8);
                #pragma unroll
                for (int j = 0; j < 8; ++j) a[j] += (float)v[j];
            }
            float* dst = &agg_msg[(size_t)rowS[s] * H + q * 8];
            #pragma unroll
            for (int j = 0; j < 8; ++j) atomicAdd(&dst[j], a[j]);
        }
    }
    __syncthreads();

    // ---- run-compressed vec aggregation ----
    const int nR = nRunsS;
    for (int it = t; it < nR * 12; it += 512) {
        const int run = it / 12, m = it % 12;
        const int s = runListS[run], e1 = runListS[run + 1];
        float a = 0.0f;
        for (int k = s; k < e1; ++k) a += coffS[k][m / 3] * unitS[k][m % 3];
        atomicAdd(&agg_vec[(size_t)rowS[s] * 12 + m], a);
    }
}

// ---------------------------------------------------------------------------
// Node kernel (MFMA): vn_feat = siluMLP(feat) + MLP(agg_mean); vn_pos
// ---------------------------------------------------------------------------
#define AOFF 0
#define BOFF 16384
#define NLDS 32768

__global__ __launch_bounds__(512, 4) void node_kernel(
    const float* __restrict__ feat, const float* __restrict__ pos,
    const _Float16* __restrict__ wf1, const float* __restrict__ fb1,
    const _Float16* __restrict__ wf2, const float* __restrict__ fb2,
    const _Float16* __restrict__ wv1, const float* __restrict__ vb1,
    const _Float16* __restrict__ wv2, const float* __restrict__ vb2,
    const float* __restrict__ agg_msg, const float* __restrict__ agg_vec,
    const int* __restrict__ cnt_i, float* __restrict__ out)
{
    __shared__ alignas(16) char Sb[NLDS];
    __shared__ float invS[64];
    char* sp = (char*)Sb;

    const int t    = threadIdx.x;
    const int lane = t & 63;
    const int w    = t >> 6;
    const int lr   = lane & 15;
    const int lk   = lane >> 4;
    const int n0   = blockIdx.x * 64;

    const float4* feat4 = (const float4*)feat;
    #pragma unroll
    for (int s = 0; s < 4; ++s) {
        const int flat = t + 512 * s;
        const int e = flat >> 5, q = flat & 31;
        const int node = n0 + e;
        float4 v = make_float4(0.f, 0.f, 0.f, 0.f);
        if (node < N_NODES) v = feat4[(size_t)node * 32 + q];
        f16x4 o; o[0]=(_Float16)v.x; o[1]=(_Float16)v.y; o[2]=(_Float16)v.z; o[3]=(_Float16)v.w;
        const int byte = (AOFF + e * HSTR + q * 8) ^ ((e & 7) << 4);
        *(f16x4*)(sp + byte) = o;
    }
    if (t < 64) {
        const int node = n0 + t;
        const float c = (node < N_NODES) ? (float)cnt_i[node] : 1.0f;
        invS[t] = fast_rcp(fmaxf(c, 1.0f));
    }
    __syncthreads();

    f32x4 acc[4];
    float resid[4][4];

    ACC_ZERO
    MFMA_GEMM(AOFF, HSTR, KS2, wf1)
    EPILOGUE(BOFF, fb1, 1)
    __syncthreads();

    ACC_ZERO
    MFMA_GEMM(BOFF, HSTR, KS2, wf2)
    {
        const float bv = fb2[w * 16 + lr];
        #pragma unroll
        for (int rt = 0; rt < 4; ++rt)
            #pragma unroll
            for (int i = 0; i < 4; ++i)
                resid[rt][i] = silu_f(acc[rt][i] + bv);
    }
    __syncthreads();

    const float4* agg4 = (const float4*)agg_msg;
    #pragma unroll
    for (int s = 0; s < 4; ++s) {
        const int flat = t + 512 * s;
        const int e = flat >> 5, q = flat & 31;
        const int node = n0 + e;
        float4 v = make_float4(0.f, 0.f, 0.f, 0.f);
        if (node < N_NODES) v = agg4[(size_t)node * 32 + q];
        const float iv = invS[e];
        f16x4 o; o[0]=(_Float16)(v.x*iv); o[1]=(_Float16)(v.y*iv);
        o[2]=(_Float16)(v.z*iv); o[3]=(_Float16)(v.w*iv);
        const int byte = (AOFF + e * HSTR + q * 8) ^ ((e & 7) << 4);
        *(f16x4*)(sp + byte) = o;
    }
    __syncthreads();

    ACC_ZERO
    MFMA_GEMM(AOFF, HSTR, KS2, wv1)
    EPILOGUE(BOFF, vb1, 1)
    __syncthreads();

    ACC_ZERO
    MFMA_GEMM(BOFF, HSTR, KS2, wv2)
    {
        const int col = w * 16 + lr;
        const float bv = vb2[col];
        #pragma unroll
        for (int rt = 0; rt < 4; ++rt) {
            #pragma unroll
            for (int i = 0; i < 4; ++i) {
                const int node = n0 + rt * 16 + lk * 4 + i;
                if (node < N_NODES)
                    out[(size_t)node * H + col] = acc[rt][i] + bv + resid[rt][i];
            }
        }
    }

    for (int fl = t; fl < 64 * 12; fl += 512) {
        const int e = fl / 12, m = fl % 12;
        const int node = n0 + e;
        if (node < N_NODES)
            out[(size_t)N_NODES * H + (size_t)node * 12 + m] =
                pos[node * 3 + (m % 3)] + agg_vec[(size_t)node * 12 + m] * invS[e];
    }
}

extern "C" void kernel_launch(void* const* d_in, const int* in_sizes, int n_in,
                              void* d_out, int out_size, void* d_ws, size_t ws_size,
                              hipStream_t stream)
{
    const float* node_feat = (const float*)d_in[0];
    const float* node_pos  = (const float*)d_in[1];
    const int*   eidx      = (const int*)  d_in[2];
    const float* eattr     = (const float*)d_in[3];
    const float* fi_w1  = (const float*)d_in[4];
    const float* fi_b1  = (const float*)d_in[5];
    const float* fi_w2  = (const float*)d_in[6];
    const float* fi_b2  = (const float*)d_in[7];
    const float* msg_w1 = (const float*)d_in[8];
    const float* msg_b1 = (const float*)d_in[9];
    const float* msg_w2 = (const float*)d_in[10];
    const float* msg_b2 = (const float*)d_in[11];
    const float* co_w1  = (const float*)d_in[12];
    const float* co_b1  = (const float*)d_in[13];
    const float* co_w2  = (const float*)d_in[14];
    const float* co_b2  = (const float*)d_in[15];
    const float* vf_w1  = (const float*)d_in[16];
    const float* vf_b1  = (const float*)d_in[17];
    const float* vf_w2  = (const float*)d_in[18];
    const float* vf_b2  = (const float*)d_in[19];

    float* out     = (float*)d_out;
    float* agg_msg = (float*)d_ws;                          // [N,128] f32
    float* agg_vec = agg_msg + (size_t)N_NODES * H;         // [N,12]  f32
    int*   cnt_i   = (int*)(agg_vec + (size_t)N_NODES * 12);// [NTOT]
    int*   offs    = cnt_i + NTOT;
    int*   cursor  = offs + NTOT;
    int*   bsum    = cursor + NTOT;                         // [256]
    int*   perm    = bsum + 256;                            // [E]
    _Float16* pr16 = (_Float16*)(perm + N_EDGES);           // [N,128]
    _Float16* pc16 = pr16 + (size_t)N_NODES * H;            // [N,128]
    _Float16* wR   = pc16 + (size_t)N_NODES * H;            // 16384
    _Float16* wC   = wR + 16384;
    _Float16* wEA  = wC + 16384;                            // 4096
    _Float16* wpk2 = wEA + 4096;
    _Float16* wpk3 = wpk2 + 16384;
    _Float16* wpk4 = wpk3 + 16384;                          // 2048
    _Float16* wF1  = wpk4 + 2048;
    _Float16* wF2  = wF1 + 16384;
    _Float16* wV1  = wF2 + 16384;
    _Float16* wV2  = wV1 + 16384;
    float*    wip  = (float*)(wV2 + 16384);                 // [128]

    hipMemsetAsync(d_ws, 0,
                   ((size_t)N_NODES * (H + 12) + NTOT) * sizeof(float), stream);

    pack_all<<<537, 256, 0, stream>>>(msg_w1, msg_w2, co_w1, co_w2,
                                      fi_w1, fi_w2, vf_w1, vf_w2,
                                      wR, wC, wEA, wpk2, wpk3, wpk4,
                                      wF1, wF2, wV1, wV2, wip);

    k_hist<<<N_EDGES / 256, 256, 0, stream>>>(eidx, cnt_i);
    k_scan1<<<NB, 256, 0, stream>>>(cnt_i, offs, bsum);
    k_scan2<<<1, 256, 0, stream>>>(bsum);
    k_addcur<<<NB, 256, 0, stream>>>(offs, bsum, cursor);
    k_scatter<<<N_EDGES / 256, 256, 0, stream>>>(eidx, cursor, perm);

    prc_kernel<<<(N_NODES + 63) / 64, 512, 0, stream>>>(node_feat, wR, wC, pr16, pc16);

    edge_kernel<<<N_EDGES / 64, 512, 0, stream>>>(
        pr16, pc16, node_pos, eidx, eattr, perm,
        wEA, wip, msg_b1, wpk2, msg_b2, wpk3, co_b1, wpk4, co_b2,
        agg_msg, agg_vec);

    node_kernel<<<(N_NODES + 63) / 64, 512, 0, stream>>>(
        node_feat, node_pos,
        wF1, fi_b1, wF2, fi_b2, wV1, vf_b1, wV2, vf_b2,
        agg_msg, agg_vec, cnt_i, out);
}

// Round 9
// 562.048 us; speedup vs baseline: 3.6179x; 1.0946x over previous
//
#include <hip/hip_runtime.h>
#include <math.h>

#define N_NODES 50000
#define NTOT    50176   // 196*256, padded node count for the scan
#define NB      196
#define N_EDGES 800000
#define H       128

typedef _Float16 f16x8 __attribute__((ext_vector_type(8)));
typedef _Float16 f16x4 __attribute__((ext_vector_type(4)));
typedef float    f32x4 __attribute__((ext_vector_type(4)));

#define KS2 4     // 128/32

// Edge-kernel LDS regions (byte offsets in one char array)
#define GOFF  0        // G = P_r[row]+P_c[col]  [64][128] f16 = 16 KB
#define MOFF  0        // msg (reuses dead G region)
#define HOFF2 16384    // h / h2  [64][128] f16 = 16 KB
#define EAOFF 32768    // eattr tile [64][32] f16 = 4 KB (stride 64 B, no swizzle)
#define HSTR  256
#define LDSB  36864

__device__ __forceinline__ float fast_rcp(float x) {
#if __has_builtin(__builtin_amdgcn_rcpf)
    return __builtin_amdgcn_rcpf(x);
#else
    return 1.0f / x;
#endif
}
__device__ __forceinline__ float fast_exp2(float x) {
#if __has_builtin(__builtin_amdgcn_exp2f)
    return __builtin_amdgcn_exp2f(x);
#else
    return exp2f(x);
#endif
}
__device__ __forceinline__ float silu_f(float x) {
    return x * fast_rcp(1.0f + fast_exp2(-1.44269504089f * x));
}

// ---------------------------------------------------------------------------
// Fused weight prep: f32 [K][NCOL] -> f16 frag-packed [ct][ks][lane][8]
// element (ct,ks,l,j) = W[ks*32+(l>>4)*8+j][ct*16+(l&15)], zero-padded
// ---------------------------------------------------------------------------
__device__ __forceinline__ void pack_one(const float* __restrict__ W, int K,
                                         int KP, int NCOL,
                                         _Float16* __restrict__ out, int idx) {
    const int KS = KP >> 5;
    const int j = idx & 7, l = (idx >> 3) & 63, rem = idx >> 9;
    const int ct = rem / KS, ks = rem % KS;
    const int k = ks * 32 + (l >> 4) * 8 + j;
    const int c = ct * 16 + (l & 15);
    out[idx] = (_Float16)((k < K && c < NCOL) ? W[k * NCOL + c] : 0.0f);
}

__global__ void pack_all(const float* __restrict__ msg_w1, const float* __restrict__ msg_w2,
                         const float* __restrict__ co_w1, const float* __restrict__ co_w2,
                         const float* __restrict__ fi_w1, const float* __restrict__ fi_w2,
                         const float* __restrict__ vf_w1, const float* __restrict__ vf_w2,
                         _Float16* __restrict__ wR, _Float16* __restrict__ wC,
                         _Float16* __restrict__ wEA, _Float16* __restrict__ w2,
                         _Float16* __restrict__ w3, _Float16* __restrict__ w4,
                         _Float16* __restrict__ wF1, _Float16* __restrict__ wF2,
                         _Float16* __restrict__ wV1, _Float16* __restrict__ wV2,
                         float* __restrict__ wip) {
    const int b = blockIdx.x, t = threadIdx.x;
    if      (b < 64)  pack_one(msg_w1,             128, 128, 128, wR,  b * 256 + t);
    else if (b < 128) pack_one(msg_w1 + 128 * 128, 128, 128, 128, wC,  (b - 64) * 256 + t);
    else if (b < 144) pack_one(msg_w1 + 256 * 128, 32,  32,  128, wEA, (b - 128) * 256 + t);
    else if (b < 208) pack_one(msg_w2, 128, 128, 128, w2,  (b - 144) * 256 + t);
    else if (b < 272) pack_one(co_w1,  128, 128, 128, w3,  (b - 208) * 256 + t);
    else if (b < 280) pack_one(co_w2,  128, 128, 4,   w4,  (b - 272) * 256 + t);
    else if (b < 344) pack_one(fi_w1,  128, 128, 128, wF1, (b - 280) * 256 + t);
    else if (b < 408) pack_one(fi_w2,  128, 128, 128, wF2, (b - 344) * 256 + t);
    else if (b < 472) pack_one(vf_w1,  128, 128, 128, wV1, (b - 408) * 256 + t);
    else if (b < 536) pack_one(vf_w2,  128, 128, 128, wV2, (b - 472) * 256 + t);
    else if (t < 128) wip[t] = msg_w1[288 * 128 + t] + msg_w1[289 * 128 + t]
                             + msg_w1[290 * 128 + t] + msg_w1[291 * 128 + t];
}

// ---------------------------------------------------------------------------
// Counting sort: hist -> 2-level exclusive scan -> scatter (perm)
// ---------------------------------------------------------------------------
__global__ void k_hist(const int* __restrict__ eidx, int* __restrict__ cnt) {
    const int e = blockIdx.x * 256 + threadIdx.x;
    atomicAdd(&cnt[eidx[e]], 1);
}

__global__ void k_scan1(const int* __restrict__ cnt, int* __restrict__ offs,
                        int* __restrict__ bsum) {
    __shared__ int sd[256];
    const int t = threadIdx.x;
    const int idx = blockIdx.x * 256 + t;
    const int v = cnt[idx];
    sd[t] = v;
    __syncthreads();
    for (int off = 1; off < 256; off <<= 1) {
        int x = (t >= off) ? sd[t - off] : 0;
        __syncthreads();
        sd[t] += x;
        __syncthreads();
    }
    offs[idx] = sd[t] - v;
    if (t == 255) bsum[blockIdx.x] = sd[255];
}

__global__ void k_scan2(int* __restrict__ bsum) {
    __shared__ int sd[256];
    const int t = threadIdx.x;
    const int v = (t < NB) ? bsum[t] : 0;
    sd[t] = v;
    __syncthreads();
    for (int off = 1; off < 256; off <<= 1) {
        int x = (t >= off) ? sd[t - off] : 0;
        __syncthreads();
        sd[t] += x;
        __syncthreads();
    }
    if (t < NB) bsum[t] = sd[t] - v;
}

__global__ void k_addcur(int* __restrict__ offs, const int* __restrict__ bsum,
                         int* __restrict__ cursor) {
    const int idx = blockIdx.x * 256 + threadIdx.x;
    const int v = offs[idx] + bsum[blockIdx.x];
    offs[idx] = v;
    cursor[idx] = v;
}

__global__ void k_scatter(const int* __restrict__ eidx, int* __restrict__ cursor,
                          int* __restrict__ perm) {
    const int e = blockIdx.x * 256 + threadIdx.x;
    const int p = atomicAdd(&cursor[eidx[e]], 1);
    perm[p] = e;
}

// ---------------------------------------------------------------------------
// swizzled LDS accessors (byte ^= (row&7)<<4 kills 128B-stride conflicts)
// ---------------------------------------------------------------------------
__device__ __forceinline__ f16x8 ld_frag(const char* sp, int off, int row,
                                         int strideB, int kb) {
    const int byte = (off + row * strideB + kb * 2) ^ ((row & 7) << 4);
    return *(const f16x8*)(sp + byte);
}
__device__ __forceinline__ void st_f16(char* sp, int off, int row, int col,
                                       _Float16 v) {
    const int byte = (off + row * HSTR + col * 2) ^ ((row & 7) << 4);
    *(_Float16*)(sp + byte) = v;
}
__device__ __forceinline__ float ld_f16(const char* sp, int off, int row, int col) {
    const int byte = (off + row * HSTR + col * 2) ^ ((row & 7) << 4);
    return (float)*(const _Float16*)(sp + byte);
}

// one wave: 64 rows x 16 cols (col tile = wave id w), A from LDS, B packed
#define MFMA_GEMM(OFF, STRIDEB, KS, WPK)                                      \
    {                                                                         \
        _Pragma("unroll")                                                     \
        for (int ks = 0; ks < (KS); ++ks) {                                   \
            const f16x8 b = *(const f16x8*)&(WPK)[(((w * (KS)) + ks) * 64 + lane) * 8]; \
            _Pragma("unroll")                                                 \
            for (int rt = 0; rt < 4; ++rt) {                                  \
                const f16x8 a = ld_frag(sp, (OFF), rt * 16 + lr, (STRIDEB),   \
                                        ks * 32 + lk * 8);                    \
                acc[rt] = __builtin_amdgcn_mfma_f32_16x16x32_f16(a, b, acc[rt], 0, 0, 0); \
            }                                                                 \
        }                                                                     \
    }

#define ACC_ZERO { _Pragma("unroll") for (int rt = 0; rt < 4; ++rt) acc[rt] = (f32x4)0.0f; }

// epilogue: C row = rt*16 + lk*4 + i, col = w*16 + lr
#define EPILOGUE(OFF, BIAS, ACT)                                              \
    {                                                                         \
        const int col = w * 16 + lr;                                          \
        const float bv = (BIAS)[col];                                         \
        _Pragma("unroll")                                                     \
        for (int rt = 0; rt < 4; ++rt) {                                      \
            _Pragma("unroll")                                                 \
            for (int i = 0; i < 4; ++i) {                                     \
                float v = acc[rt][i] + bv;                                    \
                if (ACT) v = silu_f(v);                                       \
                st_f16(sp, (OFF), rt * 16 + lk * 4 + i, col, (_Float16)v);    \
            }                                                                 \
        }                                                                     \
    }

// ---------------------------------------------------------------------------
// P_r / P_c precompute: pr16[n] = feat[n] @ msg_w1[0:128], pc16 = @[128:256]
// ---------------------------------------------------------------------------
__global__ __launch_bounds__(512, 4) void prc_kernel(
    const float* __restrict__ feat,
    const _Float16* __restrict__ wR, const _Float16* __restrict__ wC,
    _Float16* __restrict__ pr16, _Float16* __restrict__ pc16)
{
    __shared__ alignas(16) char Sb[16384];
    char* sp = (char*)Sb;
    const int t = threadIdx.x;
    const int lane = t & 63, w = t >> 6;
    const int lr = lane & 15, lk = lane >> 4;
    const int n0 = blockIdx.x * 64;

    const float4* feat4 = (const float4*)feat;
    #pragma unroll
    for (int s = 0; s < 4; ++s) {
        const int flat = t + 512 * s;
        const int e = flat >> 5, q = flat & 31;
        const int node = n0 + e;
        float4 v = make_float4(0.f, 0.f, 0.f, 0.f);
        if (node < N_NODES) v = feat4[(size_t)node * 32 + q];
        f16x4 o; o[0]=(_Float16)v.x; o[1]=(_Float16)v.y; o[2]=(_Float16)v.z; o[3]=(_Float16)v.w;
        const int byte = (e * HSTR + q * 8) ^ ((e & 7) << 4);
        *(f16x4*)(sp + byte) = o;
    }
    __syncthreads();

    f32x4 acc[4];
    const int col = w * 16 + lr;

    ACC_ZERO
    MFMA_GEMM(0, HSTR, KS2, wR)
    #pragma unroll
    for (int rt = 0; rt < 4; ++rt)
        #pragma unroll
        for (int i = 0; i < 4; ++i) {
            const int node = n0 + rt * 16 + lk * 4 + i;
            if (node < N_NODES) pr16[(size_t)node * H + col] = (_Float16)acc[rt][i];
        }

    ACC_ZERO
    MFMA_GEMM(0, HSTR, KS2, wC)
    #pragma unroll
    for (int rt = 0; rt < 4; ++rt)
        #pragma unroll
        for (int i = 0; i < 4; ++i) {
            const int node = n0 + rt * 16 + lk * 4 + i;
            if (node < N_NODES) pc16[(size_t)node * H + col] = (_Float16)acc[rt][i];
        }
}

// ---------------------------------------------------------------------------
// Edge kernel: G-gather -> EA-MFMA(+G+dsq*wip) -> msg/coff MFMA -> run agg
// launch_bounds (512,4): reg cap 128/wave (gfx950 unified VGPR+AGPR file;
// tighter caps spilled to scratch: (512,8)->550 MB, (512,6)->ok but tight).
// Aggregation atomics MUST be lane-consecutive f32 (one atomic/thread):
// wave-coalesced full-line atomics cost ~4 B/atomic of HBM write (r3: 34 MB);
// the 8-atomics-per-thread 32B-strided variant cost ~32 B/atomic (250 MB).
// ---------------------------------------------------------------------------
__global__ __launch_bounds__(512, 4) void edge_kernel(
    const _Float16* __restrict__ pr16, const _Float16* __restrict__ pc16,
    const float* __restrict__ pos,
    const int* __restrict__ eidx, const float* __restrict__ eattr,
    const int* __restrict__ perm,
    const _Float16* __restrict__ wEA, const float* __restrict__ wip,
    const float* __restrict__ mb1,
    const _Float16* __restrict__ wpk2, const float* __restrict__ mb2,
    const _Float16* __restrict__ wpk3, const float* __restrict__ cb1,
    const _Float16* __restrict__ wpk4, const float* __restrict__ cb2,
    float* __restrict__ agg_msg, float* __restrict__ agg_vec)
{
    __shared__ alignas(16) char Sb[LDSB];
    __shared__ float unitS[64][3];
    __shared__ float coffS[64][4];
    __shared__ float dsqS[64];
    __shared__ int   rowS[64];
    __shared__ int   colS[64];
    __shared__ int   peS[64];
    __shared__ int   runListS[65];
    __shared__ int   nRunsS;
    char* sp = (char*)Sb;

    const int t    = threadIdx.x;
    const int lane = t & 63;
    const int w    = t >> 6;
    const int lr   = lane & 15;
    const int lk   = lane >> 4;
    const int e0   = blockIdx.x * 64;

    // --- phase 0: geometry + run detection (wave 0) ---
    if (t < 64) {
        const int pe = perm[e0 + t];
        const int r = eidx[pe];
        const int c = eidx[N_EDGES + pe];
        peS[t] = pe; rowS[t] = r; colS[t] = c;
        const float dx = pos[r*3+0] - pos[c*3+0];
        const float dy = pos[r*3+1] - pos[c*3+1];
        const float dz = pos[r*3+2] - pos[c*3+2];
        const float dsq = dx*dx + dy*dy + dz*dz;
        const float inv = 1.0f / fmaxf(sqrtf(dsq), 1e-8f);
        unitS[t][0] = dx * inv;
        unitS[t][1] = dy * inv;
        unitS[t][2] = dz * inv;
        dsqS[t] = dsq;
        const int prev = __shfl_up(r, 1);
        const bool isStart = (t == 0) || (prev != r);
        const unsigned long long mask = __ballot(isStart);
        const int nR = __popcll(mask);
        if (isStart) runListS[__popcll(mask & ((1ull << t) - 1))] = t;
        if (t == 0)  nRunsS = nR;
        if (t == 63) runListS[nR] = 64;
    }
    __syncthreads();

    // --- phase 1: G = P_r[row] + P_c[col] (f16 pk-adds) + eattr tile ---
    #pragma unroll
    for (int s = 0; s < 2; ++s) {
        const int flat = t + 512 * s;          // 0..1023
        const int e = flat >> 4, q = flat & 15;
        const f16x8 a = *(const f16x8*)&pr16[(size_t)rowS[e] * H + q * 8];
        const f16x8 b = *(const f16x8*)&pc16[(size_t)colS[e] * H + q * 8];
        const f16x8 g = a + b;
        const int byte = (GOFF + e * HSTR + q * 16) ^ ((e & 7) << 4);
        *(f16x8*)(sp + byte) = g;
    }
    {   // eattr: [64][32] f16, stride 64 B (2-way bank alias = free)
        const int e = t >> 3, q = t & 7;
        const float4 v = ((const float4*)eattr)[(size_t)peS[e] * 8 + q];
        f16x4 o; o[0]=(_Float16)v.x; o[1]=(_Float16)v.y; o[2]=(_Float16)v.z; o[3]=(_Float16)v.w;
        *(f16x4*)(sp + EAOFF + e * 64 + q * 8) = o;
    }
    __syncthreads();

    f32x4 acc[4];
    const int col = w * 16 + lr;

    // ---- EA GEMM: h = silu(G + ea@W_ea + dsq*wip + mb1) ----
    ACC_ZERO
    {
        const f16x8 bEA = *(const f16x8*)&wEA[(w * 64 + lane) * 8];
        #pragma unroll
        for (int rt = 0; rt < 4; ++rt) {
            const f16x8 a = *(const f16x8*)(sp + EAOFF + (rt * 16 + lr) * 64 + lk * 16);
            acc[rt] = __builtin_amdgcn_mfma_f32_16x16x32_f16(a, bEA, acc[rt], 0, 0, 0);
        }
    }
    {
        const float bv = mb1[col];
        const float wipv = wip[col];
        #pragma unroll
        for (int rt = 0; rt < 4; ++rt)
            #pragma unroll
            for (int i = 0; i < 4; ++i) {
                const int row = rt * 16 + lk * 4 + i;
                float v = acc[rt][i] + bv + dsqS[row] * wipv + ld_f16(sp, GOFF, row, col);
                st_f16(sp, HOFF2, row, col, (_Float16)silu_f(v));
            }
    }
    __syncthreads();

    // ---- GEMM2: msg = h @ mw2 + mb2 (msg overwrites dead G region) ----
    ACC_ZERO
    MFMA_GEMM(HOFF2, HSTR, KS2, wpk2)
    EPILOGUE(MOFF, mb2, 0)
    __syncthreads();

    // ---- GEMM3: h2 = silu(msg @ cw1 + cb1), overwrite h region ----
    ACC_ZERO
    MFMA_GEMM(MOFF, HSTR, KS2, wpk3)
    EPILOGUE(HOFF2, cb1, 1)
    __syncthreads();

    // ---- GEMM4 (waves 0-3): coff = h2 @ cw2 + cb2 ----
    if (w < 4) {
        f32x4 a4 = (f32x4)0.0f;
        #pragma unroll
        for (int ks = 0; ks < 4; ++ks) {
            const f16x8 b = *(const f16x8*)&wpk4[(ks * 64 + lane) * 8];
            const f16x8 a = ld_frag(sp, HOFF2, w * 16 + lr, HSTR, ks * 32 + lk * 8);
            a4 = __builtin_amdgcn_mfma_f32_16x16x32_f16(a, b, a4, 0, 0, 0);
        }
        if (lr < 4) {
            #pragma unroll
            for (int i = 0; i < 4; ++i)
                coffS[w * 16 + lk * 4 + i][lr] = a4[i] + cb2[lr];
        }
    }

    // ---- run-compressed msg aggregation (ALL threads; waves 4-7 start now,
    //      waves 0-3 join after GEMM4). c = it&127 -> lane-consecutive f32
    //      addresses -> wave-coalesced atomics (r3-proven 34 MB pattern) ----
    const int nR = nRunsS;
    for (int it = t; it < nR * 128; it += 512) {
        const int run = it >> 7, c = it & 127;
        const int s = runListS[run], e1 = runListS[run + 1];
        float a = 0.0f;
        for (int k = s; k < e1; ++k) a += ld_f16(sp, MOFF, k, c);
        atomicAdd(&agg_msg[(size_t)rowS[s] * H + c], a);
    }
    __syncthreads();   // coffS ready

    // ---- run-compressed vec aggregation ----
    for (int it = t; it < nR * 12; it += 512) {
        const int run = it / 12, m = it % 12;
        const int s = runListS[run], e1 = runListS[run + 1];
        float a = 0.0f;
        for (int k = s; k < e1; ++k) a += coffS[k][m / 3] * unitS[k][m % 3];
        atomicAdd(&agg_vec[(size_t)rowS[s] * 12 + m], a);
    }
}

// ---------------------------------------------------------------------------
// Node kernel (MFMA): vn_feat = siluMLP(feat) + MLP(agg_mean); vn_pos
// ---------------------------------------------------------------------------
#define AOFF 0
#define BOFF 16384
#define NLDS 32768

__global__ __launch_bounds__(512, 4) void node_kernel(
    const float* __restrict__ feat, const float* __restrict__ pos,
    const _Float16* __restrict__ wf1, const float* __restrict__ fb1,
    const _Float16* __restrict__ wf2, const float* __restrict__ fb2,
    const _Float16* __restrict__ wv1, const float* __restrict__ vb1,
    const _Float16* __restrict__ wv2, const float* __restrict__ vb2,
    const float* __restrict__ agg_msg, const float* __restrict__ agg_vec,
    const int* __restrict__ cnt_i, float* __restrict__ out)
{
    __shared__ alignas(16) char Sb[NLDS];
    __shared__ float invS[64];
    char* sp = (char*)Sb;

    const int t    = threadIdx.x;
    const int lane = t & 63;
    const int w    = t >> 6;
    const int lr   = lane & 15;
    const int lk   = lane >> 4;
    const int n0   = blockIdx.x * 64;

    const float4* feat4 = (const float4*)feat;
    #pragma unroll
    for (int s = 0; s < 4; ++s) {
        const int flat = t + 512 * s;
        const int e = flat >> 5, q = flat & 31;
        const int node = n0 + e;
        float4 v = make_float4(0.f, 0.f, 0.f, 0.f);
        if (node < N_NODES) v = feat4[(size_t)node * 32 + q];
        f16x4 o; o[0]=(_Float16)v.x; o[1]=(_Float16)v.y; o[2]=(_Float16)v.z; o[3]=(_Float16)v.w;
        const int byte = (AOFF + e * HSTR + q * 8) ^ ((e & 7) << 4);
        *(f16x4*)(sp + byte) = o;
    }
    if (t < 64) {
        const int node = n0 + t;
        const float c = (node < N_NODES) ? (float)cnt_i[node] : 1.0f;
        invS[t] = fast_rcp(fmaxf(c, 1.0f));
    }
    __syncthreads();

    f32x4 acc[4];
    float resid[4][4];

    ACC_ZERO
    MFMA_GEMM(AOFF, HSTR, KS2, wf1)
    EPILOGUE(BOFF, fb1, 1)
    __syncthreads();

    ACC_ZERO
    MFMA_GEMM(BOFF, HSTR, KS2, wf2)
    {
        const float bv = fb2[w * 16 + lr];
        #pragma unroll
        for (int rt = 0; rt < 4; ++rt)
            #pragma unroll
            for (int i = 0; i < 4; ++i)
                resid[rt][i] = silu_f(acc[rt][i] + bv);
    }
    __syncthreads();

    const float4* agg4 = (const float4*)agg_msg;
    #pragma unroll
    for (int s = 0; s < 4; ++s) {
        const int flat = t + 512 * s;
        const int e = flat >> 5, q = flat & 31;
        const int node = n0 + e;
        float4 v = make_float4(0.f, 0.f, 0.f, 0.f);
        if (node < N_NODES) v = agg4[(size_t)node * 32 + q];
        const float iv = invS[e];
        f16x4 o; o[0]=(_Float16)(v.x*iv); o[1]=(_Float16)(v.y*iv);
        o[2]=(_Float16)(v.z*iv); o[3]=(_Float16)(v.w*iv);
        const int byte = (AOFF + e * HSTR + q * 8) ^ ((e & 7) << 4);
        *(f16x4*)(sp + byte) = o;
    }
    __syncthreads();

    ACC_ZERO
    MFMA_GEMM(AOFF, HSTR, KS2, wv1)
    EPILOGUE(BOFF, vb1, 1)
    __syncthreads();

    ACC_ZERO
    MFMA_GEMM(BOFF, HSTR, KS2, wv2)
    {
        const int col = w * 16 + lr;
        const float bv = vb2[col];
        #pragma unroll
        for (int rt = 0; rt < 4; ++rt) {
            #pragma unroll
            for (int i = 0; i < 4; ++i) {
                const int node = n0 + rt * 16 + lk * 4 + i;
                if (node < N_NODES)
                    out[(size_t)node * H + col] = acc[rt][i] + bv + resid[rt][i];
            }
        }
    }

    for (int fl = t; fl < 64 * 12; fl += 512) {
        const int e = fl / 12, m = fl % 12;
        const int node = n0 + e;
        if (node < N_NODES)
            out[(size_t)N_NODES * H + (size_t)node * 12 + m] =
                pos[node * 3 + (m % 3)] + agg_vec[(size_t)node * 12 + m] * invS[e];
    }
}

extern "C" void kernel_launch(void* const* d_in, const int* in_sizes, int n_in,
                              void* d_out, int out_size, void* d_ws, size_t ws_size,
                              hipStream_t stream)
{
    const float* node_feat = (const float*)d_in[0];
    const float* node_pos  = (const float*)d_in[1];
    const int*   eidx      = (const int*)  d_in[2];
    const float* eattr     = (const float*)d_in[3];
    const float* fi_w1  = (const float*)d_in[4];
    const float* fi_b1  = (const float*)d_in[5];
    const float* fi_w2  = (const float*)d_in[6];
    const float* fi_b2  = (const float*)d_in[7];
    const float* msg_w1 = (const float*)d_in[8];
    const float* msg_b1 = (const float*)d_in[9];
    const float* msg_w2 = (const float*)d_in[10];
    const float* msg_b2 = (const float*)d_in[11];
    const float* co_w1  = (const float*)d_in[12];
    const float* co_b1  = (const float*)d_in[13];
    const float* co_w2  = (const float*)d_in[14];
    const float* co_b2  = (const float*)d_in[15];
    const float* vf_w1  = (const float*)d_in[16];
    const float* vf_b1  = (const float*)d_in[17];
    const float* vf_w2  = (const float*)d_in[18];
    const float* vf_b2  = (const float*)d_in[19];

    float* out     = (float*)d_out;
    float* agg_msg = (float*)d_ws;                          // [N,128] f32
    float* agg_vec = agg_msg + (size_t)N_NODES * H;         // [N,12]  f32
    int*   cnt_i   = (int*)(agg_vec + (size_t)N_NODES * 12);// [NTOT]
    int*   offs    = cnt_i + NTOT;
    int*   cursor  = offs + NTOT;
    int*   bsum    = cursor + NTOT;                         // [256]
    int*   perm    = bsum + 256;                            // [E]
    _Float16* pr16 = (_Float16*)(perm + N_EDGES);           // [N,128]
    _Float16* pc16 = pr16 + (size_t)N_NODES * H;            // [N,128]
    _Float16* wR   = pc16 + (size_t)N_NODES * H;            // 16384
    _Float16* wC   = wR + 16384;
    _Float16* wEA  = wC + 16384;                            // 4096
    _Float16* wpk2 = wEA + 4096;
    _Float16* wpk3 = wpk2 + 16384;
    _Float16* wpk4 = wpk3 + 16384;                          // 2048
    _Float16* wF1  = wpk4 + 2048;
    _Float16* wF2  = wF1 + 16384;
    _Float16* wV1  = wF2 + 16384;
    _Float16* wV2  = wV1 + 16384;
    float*    wip  = (float*)(wV2 + 16384);                 // [128]

    hipMemsetAsync(d_ws, 0,
                   ((size_t)N_NODES * (H + 12) + NTOT) * sizeof(float), stream);

    pack_all<<<537, 256, 0, stream>>>(msg_w1, msg_w2, co_w1, co_w2,
                                      fi_w1, fi_w2, vf_w1, vf_w2,
                                      wR, wC, wEA, wpk2, wpk3, wpk4,
                                      wF1, wF2, wV1, wV2, wip);

    k_hist<<<N_EDGES / 256, 256, 0, stream>>>(eidx, cnt_i);
    k_scan1<<<NB, 256, 0, stream>>>(cnt_i, offs, bsum);
    k_scan2<<<1, 256, 0, stream>>>(bsum);
    k_addcur<<<NB, 256, 0, stream>>>(offs, bsum, cursor);
    k_scatter<<<N_EDGES / 256, 256, 0, stream>>>(eidx, cursor, perm);

    prc_kernel<<<(N_NODES + 63) / 64, 512, 0, stream>>>(node_feat, wR, wC, pr16, pc16);

    edge_kernel<<<N_EDGES / 64, 512, 0, stream>>>(
        pr16, pc16, node_pos, eidx, eattr, perm,
        wEA, wip, msg_b1, wpk2, msg_b2, wpk3, co_b1, wpk4, co_b2,
        agg_msg, agg_vec);

    node_kernel<<<(N_NODES + 63) / 64, 512, 0, stream>>>(
        node_feat, node_pos,
        wF1, fi_b1, wF2, fi_b2, wV1, vf_b1, wV2, vf_b2,
        agg_msg, agg_vec, cnt_i, out);
}